// Round 15
// baseline (147.679 us; speedup 1.0000x reference)
//
#include <hip/hip_runtime.h>
#include <hip/hip_bf16.h>

typedef __attribute__((ext_vector_type(8))) short short8v;
typedef __attribute__((ext_vector_type(4))) float f32x4;

__device__ __forceinline__ short f2bf(float f){
  unsigned u = __builtin_bit_cast(unsigned, f);
  u += 0x7fffu + ((u >> 16) & 1u);
  return (short)(u >> 16);
}
__device__ __forceinline__ float bf2f(unsigned short s){
  unsigned u = ((unsigned)s) << 16;
  return __builtin_bit_cast(float, u);
}

__device__ __forceinline__ void gload16(const short* g, short* l){
  __builtin_amdgcn_global_load_lds(
    (const __attribute__((address_space(1))) unsigned int*)g,
    (__attribute__((address_space(3))) unsigned int*)l,
    16, 0, 0);
}

// ---------------- fused prep: cast s, wbbf table, both weight transposes ----------------
__global__ __launch_bounds__(256) void prep_kernel(
    const float* __restrict__ s, const float* __restrict__ w_b,
    const float* __restrict__ wq, const float* __restrict__ wk, const float* __restrict__ wv,
    const float* __restrict__ wqp, const float* __restrict__ wkp, const float* __restrict__ wvp,
    const float* __restrict__ w_out,
    short* __restrict__ s_bf, short* __restrict__ wbbf,
    short* __restrict__ WT, short* __restrict__ w_outT)
{
  __shared__ float tsh[64][65];
  int b = blockIdx.x;
  if (b < 192) {
    int gid = b*256 + threadIdx.x;
    float4 f = *(const float4*)(s + (size_t)gid*4);
    short4 o = make_short4(f2bf(f.x), f2bf(f.y), f2bf(f.z), f2bf(f.w));
    *(short4*)(s_bf + (size_t)gid*4) = o;
  } else if (b == 192) {
    const float wL = 0.57735026918962576f;
    for (int u = threadIdx.x; u < 2048; u += 256) {
      int h = u >> 7, zc = u & 127;
      float v = (h < 12) ? w_b[zc*12 + h]*wL : 0.f;
      wbbf[u] = f2bf(v);
    }
  } else if (b < 373) {
    int t = b - 193;
    int n0 = (t % 5)*64, k0 = ((t/5) % 6)*64, src = t/30;
    const float* in; int N; int rowoff;
    switch (src) {
      case 0: in = wq;  N = 192; rowoff = 0;   break;
      case 1: in = wk;  N = 192; rowoff = 192; break;
      case 2: in = wv;  N = 192; rowoff = 384; break;
      case 3: in = wqp; N = 144; rowoff = 576; break;
      case 4: in = wkp; N = 144; rowoff = 720; break;
      default:in = wvp; N = 288; rowoff = 864; break;
    }
    if (n0 >= N) return;
    int lx = threadIdx.x & 15, ly = threadIdx.x >> 4;
    #pragma unroll
    for (int p=0;p<4;++p){
      int r = ly + p*16, c = lx*4;
      float v0=0.f,v1=0.f,v2=0.f,v3=0.f;
      if (n0 + c + 3 < N) {
        float4 v = *(const float4*)(in + (size_t)(k0+r)*N + n0 + c);
        v0=v.x; v1=v.y; v2=v.z; v3=v.w;
      } else {
        if (n0+c+0 < N) v0 = in[(size_t)(k0+r)*N + n0+c+0];
        if (n0+c+1 < N) v1 = in[(size_t)(k0+r)*N + n0+c+1];
        if (n0+c+2 < N) v2 = in[(size_t)(k0+r)*N + n0+c+2];
        if (n0+c+3 < N) v3 = in[(size_t)(k0+r)*N + n0+c+3];
      }
      tsh[c+0][r]=v0; tsh[c+1][r]=v1; tsh[c+2][r]=v2; tsh[c+3][r]=v3;
    }
    __syncthreads();
    #pragma unroll
    for (int p=0;p<4;++p){
      int nr = ly + p*16, kc = lx*4;
      if (n0 + nr < N) {
        short4 o = make_short4(f2bf(tsh[nr][kc]), f2bf(tsh[nr][kc+1]),
                               f2bf(tsh[nr][kc+2]), f2bf(tsh[nr][kc+3]));
        *(short4*)(WT + (size_t)(rowoff+n0+nr)*384 + k0 + kc) = o;
      }
    }
  } else {
    int t = b - 373;
    int n0 = (t % 6)*64, k0 = (t/6)*64;
    int lx = threadIdx.x & 15, ly = threadIdx.x >> 4;
    #pragma unroll
    for (int p=0;p<4;++p){
      int r = ly + p*16, c = lx*4;
      float4 v = *(const float4*)(w_out + (size_t)(k0+r)*384 + n0 + c);
      tsh[c+0][r]=v.x; tsh[c+1][r]=v.y; tsh[c+2][r]=v.z; tsh[c+3][r]=v.w;
    }
    __syncthreads();
    #pragma unroll
    for (int p=0;p<4;++p){
      int nr = ly + p*16, kc = lx*4;
      short4 o = make_short4(f2bf(tsh[nr][kc]), f2bf(tsh[nr][kc+1]),
                             f2bf(tsh[nr][kc+2]), f2bf(tsh[nr][kc+3]));
      *(short4*)(w_outT + (size_t)(n0+nr)*2112 + k0 + kc) = o;
    }
  }
}

// ---------------- bf16 MFMA GEMM: C[M][N] = A[M][K] @ BT[N][K]^T ----------------
__global__ __launch_bounds__(256) void gemm_bf16_kernel(
    const short* __restrict__ A, const short* __restrict__ BT,
    float* __restrict__ C, const float* __restrict__ bias,
    int M, int N, int K)
{
  __shared__ __align__(16) short As[2][4096];
  __shared__ __align__(16) short Bs[2][4096];
  int tid = threadIdx.x;
  int n0 = blockIdx.x*128, m0 = blockIdx.y*128;
  int w = tid >> 6, lane = tid & 63;
  int wr = w >> 1, wc = w & 1;
  int lrow = lane & 15, kg = lane >> 4;
  int nt = K >> 5;
  f32x4 acc[4][4] = {};

  const short* Abase = A  + (size_t)m0*K;
  const short* Bbase = BT + (size_t)n0*K;
  int sr = tid >> 2, scc = (tid & 3)*8;

  auto stage = [&](int b, int k0){
    const short* Ab = Abase + k0;
    const short* Bb = Bbase + k0;
    gload16(Ab + (size_t)sr*K + scc,      &As[b][tid*8]);
    gload16(Bb + (size_t)sr*K + scc,      &Bs[b][tid*8]);
    gload16(Ab + (size_t)(sr+64)*K + scc, &As[b][2048 + tid*8]);
    gload16(Bb + (size_t)(sr+64)*K + scc, &Bs[b][2048 + tid*8]);
  };

  stage(0, 0);
  for (int kt = 0; kt < nt; ++kt){
    int cb = kt & 1;
    if (kt + 1 < nt){
      stage(cb ^ 1, (kt+1) << 5);
      asm volatile("s_waitcnt vmcnt(4)" ::: "memory");
    } else {
      asm volatile("s_waitcnt vmcnt(0)" ::: "memory");
    }
    __builtin_amdgcn_s_barrier();
    short8v af[4], bfr[4];
    #pragma unroll
    for (int mi=0; mi<4; ++mi)
      af[mi]  = *(const short8v*)&As[cb][(wr*64 + mi*16 + lrow)*32 + kg*8];
    #pragma unroll
    for (int ni=0; ni<4; ++ni)
      bfr[ni] = *(const short8v*)&Bs[cb][(wc*64 + ni*16 + lrow)*32 + kg*8];
    #pragma unroll
    for (int mi=0; mi<4; ++mi)
      #pragma unroll
      for (int ni=0; ni<4; ++ni)
        acc[mi][ni] = __builtin_amdgcn_mfma_f32_16x16x32_bf16(af[mi], bfr[ni], acc[mi][ni], 0, 0, 0);
    __builtin_amdgcn_s_barrier();
  }

  #pragma unroll
  for (int mi=0; mi<4; ++mi)
    #pragma unroll
    for (int ni=0; ni<4; ++ni) {
      int col = n0 + wc*64 + ni*16 + lrow;
      float bv = bias ? bias[col] : 0.f;
      #pragma unroll
      for (int jj=0; jj<4; ++jj) {
        int row = m0 + wr*64 + mi*16 + kg*4 + jj;
        C[(size_t)row*N + col] = acc[mi][ni][jj] + bv;
      }
    }
}

// ---------------- split-K GEMM ----------------
__global__ __launch_bounds__(256) void gemm_splitk_kernel(
    const short* __restrict__ A, const short* __restrict__ BT,
    float* __restrict__ Cpart, int M, int N, int lda, int Kc)
{
  __shared__ __align__(16) short As[2][4096];
  __shared__ __align__(16) short Bs[2][4096];
  int tid = threadIdx.x;
  int n0 = blockIdx.x*128, m0 = blockIdx.y*128;
  int kb = blockIdx.z;
  int w = tid >> 6, lane = tid & 63;
  int wr = w >> 1, wc = w & 1;
  int lrow = lane & 15, kg = lane >> 4;
  int nt = Kc >> 5;
  f32x4 acc[4][4] = {};

  const short* Abase = A  + (size_t)m0*lda + (size_t)kb*Kc;
  const short* Bbase = BT + (size_t)n0*lda + (size_t)kb*Kc;
  int sr = tid >> 2, scc = (tid & 3)*8;

  auto stage = [&](int b, int k0){
    const short* Ab = Abase + k0;
    const short* Bb = Bbase + k0;
    gload16(Ab + (size_t)sr*lda + scc,      &As[b][tid*8]);
    gload16(Bb + (size_t)sr*lda + scc,      &Bs[b][tid*8]);
    gload16(Ab + (size_t)(sr+64)*lda + scc, &As[b][2048 + tid*8]);
    gload16(Bb + (size_t)(sr+64)*lda + scc, &Bs[b][2048 + tid*8]);
  };

  stage(0, 0);
  for (int kt = 0; kt < nt; ++kt){
    int cb = kt & 1;
    if (kt + 1 < nt){
      stage(cb ^ 1, (kt+1) << 5);
      asm volatile("s_waitcnt vmcnt(4)" ::: "memory");
    } else {
      asm volatile("s_waitcnt vmcnt(0)" ::: "memory");
    }
    __builtin_amdgcn_s_barrier();
    short8v af[4], bfr[4];
    #pragma unroll
    for (int mi=0; mi<4; ++mi)
      af[mi]  = *(const short8v*)&As[cb][(wr*64 + mi*16 + lrow)*32 + kg*8];
    #pragma unroll
    for (int ni=0; ni<4; ++ni)
      bfr[ni] = *(const short8v*)&Bs[cb][(wc*64 + ni*16 + lrow)*32 + kg*8];
    #pragma unroll
    for (int mi=0; mi<4; ++mi)
      #pragma unroll
      for (int ni=0; ni<4; ++ni)
        acc[mi][ni] = __builtin_amdgcn_mfma_f32_16x16x32_bf16(af[mi], bfr[ni], acc[mi][ni], 0, 0, 0);
    __builtin_amdgcn_s_barrier();
  }

  float* Cp = Cpart + (size_t)kb*M*N;
  #pragma unroll
  for (int mi=0; mi<4; ++mi)
    #pragma unroll
    for (int ni=0; ni<4; ++ni) {
      int col = n0 + wc*64 + ni*16 + lrow;
      #pragma unroll
      for (int jj=0; jj<4; ++jj) {
        int row = m0 + wr*64 + mi*16 + kg*4 + jj;
        Cp[(size_t)row*N + col] = acc[mi][ni][jj];
      }
    }
}

// ---------------- reduce 6 split-K partials + bias ----------------
__global__ __launch_bounds__(256) void reduce6_kernel(
    const float* __restrict__ Cpart, const float* __restrict__ bias,
    float* __restrict__ out)
{
  int idx = blockIdx.x*256 + threadIdx.x;   // 196608 total
  float v = bias[idx % 384];
  #pragma unroll
  for (int zc = 0; zc < 6; ++zc) v += Cpart[(size_t)zc*196608 + idx];
  out[idx] = v;
}

// ---------------- transform: P -> kT, kpgT, qpg, vcatT (LDS-staged, coalesced) ----------------
__global__ __launch_bounds__(256) void transform_kernel(
    const float* __restrict__ P, const float* __restrict__ T,
    float* __restrict__ kT, float* __restrict__ kpgT,
    float* __restrict__ qpg, unsigned short* __restrict__ vcatT)
{
  __shared__ float Ps[8][1160];
  __shared__ float Ts[8][12];
  int tid = threadIdx.x;
  int j0 = blockIdx.x*8;
  for (int u = tid; u < 8*288; u += 256) {
    int r = u / 288, c4 = u % 288;
    *(float4*)&Ps[r][c4*4] = *(const float4*)(P + (size_t)(j0+r)*1152 + c4*4);
  }
  if (tid < 96) {
    int r = tid / 12, e = tid % 12;
    Ts[r][e] = (e < 9) ? T[(j0+r)*16 + (e/3)*4 + (e%3)]
                       : T[(j0+r)*16 + (e-9)*4 + 3];
  }
  __syncthreads();
  for (int u = tid; u < 1536; u += 256) {
    int row = u >> 3, jl = u & 7;
    kT[(size_t)row*512 + j0 + jl] = Ps[jl][192 + row];
  }
  for (int u = tid; u < 1152; u += 256) {
    int e = u >> 3, jl = u & 7;
    int x = e % 3, hp = e / 3;
    const float* R = &Ts[jl][0];
    float kx = Ps[jl][720+hp*3], ky = Ps[jl][720+hp*3+1], kz = Ps[jl][720+hp*3+2];
    kpgT[(size_t)e*512 + j0 + jl] = R[x*3]*kx + R[x*3+1]*ky + R[x*3+2]*kz + Ts[jl][9+x];
  }
  for (int u = tid; u < 1152; u += 256) {
    int jl = u / 144, e = u % 144;
    int x = e % 3, hp = e / 3;
    const float* R = &Ts[jl][0];
    float qx = Ps[jl][576+hp*3], qy = Ps[jl][576+hp*3+1], qz = Ps[jl][576+hp*3+2];
    qpg[(size_t)(j0+jl)*144 + e] = R[x*3]*qx + R[x*3+1]*qy + R[x*3+2]*qz + Ts[jl][9+x];
  }
  for (int u = tid; u < 3840; u += 256) {
    int d = u >> 3, jl = u & 7;
    float val;
    if (d < 192) val = Ps[jl][384 + d];
    else {
      int e = d - 192;
      int x = e % 3, hp = e / 3;
      const float* R = &Ts[jl][0];
      float vx = Ps[jl][864+hp*3], vy = Ps[jl][864+hp*3+1], vz = Ps[jl][864+hp*3+2];
      val = R[x*3]*vx + R[x*3+1]*vy + R[x*3+2]*vz + Ts[jl][9+x];
    }
    vcatT[(size_t)d*512 + j0 + jl] = (unsigned short)f2bf(val);
  }
}

// ---------------- attn partials: block = (i, jq), 128 j each; bias + o_pair MFMA ----------------
// part layout per block (stride 2048 f32):
//   [0:12) m, [12:24) S, [24:216) o, [216:504) opg, [512:2048) o_pair f32
__global__ __launch_bounds__(256) void attn_part_kernel(
    const float* __restrict__ P, const float* __restrict__ qpg,
    const float* __restrict__ kT, const float* __restrict__ kpgT,
    const short* __restrict__ wbbf, const float* __restrict__ z,
    const unsigned short* __restrict__ vcatT,
    const float* __restrict__ gamma, float* __restrict__ part)
{
  __shared__ short zbT[16384];                 // swizzled bf16 z^T [zc][j]
  __shared__ float sc[12][132];
  __shared__ float qrow[192], qpgrow[144], gsp[12];
  int bid = blockIdx.x;
  int i = bid >> 2, jq = bid & 3;
  int j0 = jq * 128;
  int tid = threadIdx.x;
  float* pb = part + (size_t)bid * 2048;
  const float* zslab = z + (size_t)i*65536 + (size_t)j0*128;  // [128 j][128 zc]

  if (tid < 192) qrow[tid] = P[(size_t)i*1152 + tid];
  if (tid < 144) qpgrow[tid] = qpg[(size_t)i*144 + tid];
  if (tid < 12)  { float g = gamma[tid]; gsp[tid] = log1pf(__expf(g)); }

  // P0a: stage zbT bf16 with 16B-chunk XOR swizzle (chunk ^= (zc&15)^(zc>>4))
  {
    int q = tid & 31, jb = tid >> 5;
    for (int r = 0; r < 16; ++r) {
      int jj = jb + r*8;
      float4 f = *(const float4*)(zslab + (size_t)jj*128 + q*4);
      short wv0 = f2bf(f.x), wv1 = f2bf(f.y), wv2 = f2bf(f.z), wv3 = f2bf(f.w);
      int jc = jj >> 3, jr = jj & 7;
      int zc = q*4;
      zbT[(zc+0)*128 + ((jc ^ (((zc+0)&15)^((zc+0)>>4))) << 3) + jr] = wv0;
      zbT[(zc+1)*128 + ((jc ^ (((zc+1)&15)^((zc+1)>>4))) << 3) + jr] = wv1;
      zbT[(zc+2)*128 + ((jc ^ (((zc+2)&15)^((zc+2)>>4))) << 3) + jr] = wv2;
      zbT[(zc+3)*128 + ((jc ^ (((zc+3)&15)^((zc+3)>>4))) << 3) + jr] = wv3;
    }
  }

  // P0b: bias via skinny MFMA — seed sc[h][j] with wL*(z@w_b)
  {
    int w = tid >> 6, lane = tid & 63;
    int lrow = lane & 15, kg = lane >> 4;
    #pragma unroll
    for (int sub = 0; sub < 2; ++sub) {
      int m = w*2 + sub;
      const float* zr = zslab + (size_t)(m*16 + lrow)*128;
      f32x4 acc = {0.f,0.f,0.f,0.f};
      #pragma unroll
      for (int ks = 0; ks < 4; ++ks) {
        int c0 = ks*32 + kg*8;
        float4 z0 = *(const float4*)(zr + c0);
        float4 z1 = *(const float4*)(zr + c0 + 4);
        short8v af;
        af[0]=f2bf(z0.x); af[1]=f2bf(z0.y); af[2]=f2bf(z0.z); af[3]=f2bf(z0.w);
        af[4]=f2bf(z1.x); af[5]=f2bf(z1.y); af[6]=f2bf(z1.z); af[7]=f2bf(z1.w);
        short8v bfv = *(const short8v*)(wbbf + lrow*128 + c0);
        acc = __builtin_amdgcn_mfma_f32_16x16x32_bf16(af, bfv, acc, 0, 0, 0);
      }
      if (lrow < 12) {
        #pragma unroll
        for (int r=0;r<4;++r)
          sc[lrow][m*16 + kg*4 + r] = acc[r];
      }
    }
  }
  __syncthreads();

  // P1: logits for 12 heads over this j-slice (sc pre-seeded with bias)
  {
    int j = tid & 127, hh = tid >> 7;
    const float wL = 0.57735026918962576f;
    const float wC = 0.23570226039551584f;
    #pragma unroll
    for (int hl = 0; hl < 6; ++hl) {
      int h = hh*6 + hl;
      float dot = 0.f;
      #pragma unroll
      for (int c=0;c<16;++c) dot += qrow[h*16+c] * kT[(size_t)(h*16+c)*512 + j0 + j];
      float d2 = 0.f;
      #pragma unroll
      for (int e=0;e<12;++e){ float d = qpgrow[h*12+e] - kpgT[(size_t)(h*12+e)*512 + j0 + j]; d2 += d*d; }
      sc[h][j] += wL*(dot*0.25f - 0.5f*gsp[h]*wC*d2);
    }
  }
  __syncthreads();

  // P2: partial softmax per head: local max m, unnormalized p, local sum S
  if (tid < 192) {
    int h = tid >> 4, l = tid & 15;
    float v[8]; float m = -1e30f;
    #pragma unroll
    for (int u=0;u<8;++u){ v[u] = sc[h][l + u*16]; m = fmaxf(m, v[u]); }
    #pragma unroll
    for (int s2=1;s2<16;s2<<=1) m = fmaxf(m, __shfl_xor(m, s2));
    float sum = 0.f;
    #pragma unroll
    for (int u=0;u<8;++u){ v[u] = __expf(v[u]-m); sum += v[u]; sc[h][l + u*16] = v[u]; }
    #pragma unroll
    for (int s2=1;s2<16;s2<<=1) sum += __shfl_xor(sum, s2);
    if (l == 0) { pb[h] = m; pb[12+h] = sum; }
  }
  __syncthreads();

  // P3: o+opg partials — wave per 120 d-rows, lane per j-pair, shuffle-reduce.
  // Each wave-instruction touches 2 cache lines (vs 64 in the d-major b128 form).
  {
    int w = tid >> 6, lane = tid & 63;
    for (int t = 0; t < 120; t += 4) {
      float acc[4];
      #pragma unroll
      for (int q = 0; q < 4; ++q) {
        int d = w*120 + t + q;
        int h = (d < 192) ? (d >> 4) : ((d - 192) / 24);
        unsigned int vv = *(const unsigned int*)(vcatT + (size_t)d*512 + j0 + lane*2);
        float2 av = *(const float2*)&sc[h][lane*2];
        acc[q] = av.x*bf2f((unsigned short)(vv & 0xffffu))
               + av.y*bf2f((unsigned short)(vv >> 16));
      }
      #pragma unroll
      for (int q = 0; q < 4; ++q) {
        #pragma unroll
        for (int s2 = 32; s2 > 0; s2 >>= 1) acc[q] += __shfl_xor(acc[q], s2);
      }
      #pragma unroll
      for (int q = 0; q < 4; ++q)
        if (lane == q) pb[24 + w*120 + t + q] = acc[q];
    }
  }

  // P4: partial o_pair = sc @ z via MFMA (A = sc rows, B = zbT swizzled)
  {
    int w = tid >> 6, lane = tid & 63;
    int lrow = lane & 15, kg = lane >> 4;
    short8v afr[4];
    #pragma unroll
    for (int ks = 0; ks < 4; ++ks) {
      int row = lrow < 12 ? lrow : 11;
      const float* sp = &sc[row][ks*32 + kg*8];
      float4 a0 = *(const float4*)sp;
      float4 a1 = *(const float4*)(sp+4);
      short8v a;
      a[0]=f2bf(a0.x); a[1]=f2bf(a0.y); a[2]=f2bf(a0.z); a[3]=f2bf(a0.w);
      a[4]=f2bf(a1.x); a[5]=f2bf(a1.y); a[6]=f2bf(a1.z); a[7]=f2bf(a1.w);
      afr[ks] = a;
    }
    #pragma unroll
    for (int t = 0; t < 2; ++t) {
      int zc = w*32 + t*16 + lrow;
      int sw = (zc & 15) ^ (zc >> 4);
      f32x4 pacc = {0.f,0.f,0.f,0.f};
      #pragma unroll
      for (int ks = 0; ks < 4; ++ks) {
        int chunk = (ks*4 + kg) ^ sw;
        short8v bfv = *(const short8v*)&zbT[zc*128 + (chunk<<3)];
        pacc = __builtin_amdgcn_mfma_f32_16x16x32_bf16(afr[ks], bfv, pacc, 0, 0, 0);
      }
      if (kg < 3) {
        #pragma unroll
        for (int r = 0; r < 4; ++r) {
          int h = kg*4 + r;
          pb[512 + h*128 + zc] = pacc[r];
        }
      }
    }
  }
}

// ---------------- combine partials -> cat row ----------------
__global__ __launch_bounds__(256) void combine_kernel(
    const float* __restrict__ part, const float* __restrict__ T,
    short* __restrict__ cat)
{
  __shared__ float w4[4][12], inv[12];
  __shared__ float opgf[288];
  __shared__ float Ri[9], ti[3];
  int i = blockIdx.x, tid = threadIdx.x;
  const float* pb = part + (size_t)i * 4 * 2048;

  if (tid < 12) {
    float m0 = pb[tid], m1 = pb[2048+tid], m2 = pb[4096+tid], m3 = pb[6144+tid];
    float mh = fmaxf(fmaxf(m0,m1), fmaxf(m2,m3));
    float w0 = __expf(m0-mh), w1 = __expf(m1-mh), w2 = __expf(m2-mh), w3 = __expf(m3-mh);
    float S = w0*pb[12+tid] + w1*pb[2060+tid] + w2*pb[4108+tid] + w3*pb[6156+tid];
    w4[0][tid]=w0; w4[1][tid]=w1; w4[2][tid]=w2; w4[3][tid]=w3;
    inv[tid] = 1.f/S;
  }
  if (tid >= 64 && tid < 73) { int e = tid-64; Ri[e] = T[i*16 + (e/3)*4 + (e%3)]; }
  if (tid >= 76 && tid < 79) { int e = tid-76; ti[e] = T[i*16 + e*4 + 3]; }
  __syncthreads();

  short* crow = cat + (size_t)i*2112;

  if (tid < 192) {
    int h = tid >> 4;
    float v = w4[0][h]*pb[24+tid] + w4[1][h]*pb[2072+tid]
            + w4[2][h]*pb[4120+tid] + w4[3][h]*pb[6168+tid];
    crow[tid] = f2bf(v * inv[h]);
  }
  for (int u = tid; u < 288; u += 256) {
    int h = u / 24;
    float v = w4[0][h]*pb[216+u] + w4[1][h]*pb[2264+u]
            + w4[2][h]*pb[4312+u] + w4[3][h]*pb[6360+u];
    opgf[u] = v * inv[h];
  }
  __syncthreads();
  if (tid < 96) {
    float d0 = opgf[tid*3+0]-ti[0], d1 = opgf[tid*3+1]-ti[1], d2v = opgf[tid*3+2]-ti[2];
    float o0 = Ri[0]*d0 + Ri[3]*d1 + Ri[6]*d2v;
    float o1 = Ri[1]*d0 + Ri[4]*d1 + Ri[7]*d2v;
    float o2 = Ri[2]*d0 + Ri[5]*d1 + Ri[8]*d2v;
    crow[192+tid*3+0] = f2bf(o0); crow[192+tid*3+1] = f2bf(o1); crow[192+tid*3+2] = f2bf(o2);
    crow[480+tid] = f2bf(sqrtf(o0*o0 + o1*o1 + o2*o2 + 1e-8f));
  }
  for (int u = tid; u < 1536; u += 256) {
    int h = u >> 7;
    float v = w4[0][h]*pb[512+u] + w4[1][h]*pb[2560+u]
            + w4[2][h]*pb[4608+u] + w4[3][h]*pb[6656+u];
    crow[576+u] = f2bf(v * inv[h]);
  }
}

// ---------------- launch ----------------
extern "C" void kernel_launch(void* const* d_in, const int* in_sizes, int n_in,
                              void* d_out, int out_size, void* d_ws, size_t ws_size,
                              hipStream_t stream) {
  const float* s     = (const float*)d_in[0];
  const float* z     = (const float*)d_in[1];
  const float* T     = (const float*)d_in[2];
  const float* w_q   = (const float*)d_in[3];
  const float* w_k   = (const float*)d_in[4];
  const float* w_v   = (const float*)d_in[5];
  const float* w_qp  = (const float*)d_in[6];
  const float* w_kp  = (const float*)d_in[7];
  const float* w_vp  = (const float*)d_in[8];
  const float* w_b   = (const float*)d_in[9];
  const float* gamma = (const float*)d_in[10];
  const float* w_out = (const float*)d_in[11];
  const float* b_out = (const float*)d_in[12];

  float* ws = (float*)d_ws;
  float* P      = ws;                        // 589824
  float* kT     = ws + 589824;               // 98304
  float* kpgT   = ws + 688128;               // 73728
  float* qpg    = ws + 761856;               // 73728
  short* wbbf   = (short*)(ws + 835584);     // 2048 sh (1024 f)
  short* s_bf   = (short*)(ws + 836608);     // 196608 sh (98304 f)
  short* WT     = (short*)(ws + 934912);     // 442368 sh (221184 f)
  short* w_outT = (short*)(ws + 1156096);    // 811008 sh (405504 f)
  unsigned short* vcatT = (unsigned short*)(ws + 1561600); // 245760 sh (122880 f)
  short* cat    = (short*)(ws + 1684480);    // 1081344 sh (540672 f)
  float* partb  = ws + 2225152;              // 2048*2048 = 4194304 f
  float* Cpart  = ws + 6419456;              // 6*196608 = 1179648 f

  prep_kernel<<<571, 256, 0, stream>>>(s, w_b, w_q, w_k, w_v, w_qp, w_kp, w_vp, w_out,
                                       s_bf, wbbf, WT, w_outT);
  gemm_bf16_kernel<<<dim3(9,4), 256, 0, stream>>>(s_bf, WT, P, nullptr, 512, 1152, 384);
  transform_kernel<<<64, 256, 0, stream>>>(P, T, kT, kpgT, qpg, vcatT);
  attn_part_kernel<<<2048, 256, 0, stream>>>(P, qpg, kT, kpgT, wbbf, z, vcatT, gamma, partb);
  combine_kernel<<<512, 256, 0, stream>>>(partb, T, cat);
  gemm_splitk_kernel<<<dim3(3,4,6), 256, 0, stream>>>(cat, w_outT, Cpart, 512, 384, 2112, 352);
  reduce6_kernel<<<768, 256, 0, stream>>>(Cpart, b_out, (float*)d_out);
}

// Round 16
// 116.999 us; speedup vs baseline: 1.2622x; 1.2622x over previous
//
#include <hip/hip_runtime.h>
#include <hip/hip_bf16.h>

typedef __attribute__((ext_vector_type(8))) short short8v;
typedef __attribute__((ext_vector_type(4))) float f32x4;

__device__ __forceinline__ short f2bf(float f){
  unsigned u = __builtin_bit_cast(unsigned, f);
  u += 0x7fffu + ((u >> 16) & 1u);
  return (short)(u >> 16);
}
__device__ __forceinline__ float bf2f(unsigned short s){
  unsigned u = ((unsigned)s) << 16;
  return __builtin_bit_cast(float, u);
}

__device__ __forceinline__ void gload16(const short* g, short* l){
  __builtin_amdgcn_global_load_lds(
    (const __attribute__((address_space(1))) unsigned int*)g,
    (__attribute__((address_space(3))) unsigned int*)l,
    16, 0, 0);
}

// ---------------- fused prep: cast s, wbbf table, both weight transposes ----------------
__global__ __launch_bounds__(256) void prep_kernel(
    const float* __restrict__ s, const float* __restrict__ w_b,
    const float* __restrict__ wq, const float* __restrict__ wk, const float* __restrict__ wv,
    const float* __restrict__ wqp, const float* __restrict__ wkp, const float* __restrict__ wvp,
    const float* __restrict__ w_out,
    short* __restrict__ s_bf, short* __restrict__ wbbf,
    short* __restrict__ WT, short* __restrict__ w_outT)
{
  __shared__ float tsh[64][65];
  int b = blockIdx.x;
  if (b < 192) {
    int gid = b*256 + threadIdx.x;
    float4 f = *(const float4*)(s + (size_t)gid*4);
    short4 o = make_short4(f2bf(f.x), f2bf(f.y), f2bf(f.z), f2bf(f.w));
    *(short4*)(s_bf + (size_t)gid*4) = o;
  } else if (b == 192) {
    const float wL = 0.57735026918962576f;
    for (int u = threadIdx.x; u < 2048; u += 256) {
      int h = u >> 7, zc = u & 127;
      float v = (h < 12) ? w_b[zc*12 + h]*wL : 0.f;
      wbbf[u] = f2bf(v);
    }
  } else if (b < 373) {
    int t = b - 193;
    int n0 = (t % 5)*64, k0 = ((t/5) % 6)*64, src = t/30;
    const float* in; int N; int rowoff;
    switch (src) {
      case 0: in = wq;  N = 192; rowoff = 0;   break;
      case 1: in = wk;  N = 192; rowoff = 192; break;
      case 2: in = wv;  N = 192; rowoff = 384; break;
      case 3: in = wqp; N = 144; rowoff = 576; break;
      case 4: in = wkp; N = 144; rowoff = 720; break;
      default:in = wvp; N = 288; rowoff = 864; break;
    }
    if (n0 >= N) return;
    int lx = threadIdx.x & 15, ly = threadIdx.x >> 4;
    #pragma unroll
    for (int p=0;p<4;++p){
      int r = ly + p*16, c = lx*4;
      float v0=0.f,v1=0.f,v2=0.f,v3=0.f;
      if (n0 + c + 3 < N) {
        float4 v = *(const float4*)(in + (size_t)(k0+r)*N + n0 + c);
        v0=v.x; v1=v.y; v2=v.z; v3=v.w;
      } else {
        if (n0+c+0 < N) v0 = in[(size_t)(k0+r)*N + n0+c+0];
        if (n0+c+1 < N) v1 = in[(size_t)(k0+r)*N + n0+c+1];
        if (n0+c+2 < N) v2 = in[(size_t)(k0+r)*N + n0+c+2];
        if (n0+c+3 < N) v3 = in[(size_t)(k0+r)*N + n0+c+3];
      }
      tsh[c+0][r]=v0; tsh[c+1][r]=v1; tsh[c+2][r]=v2; tsh[c+3][r]=v3;
    }
    __syncthreads();
    #pragma unroll
    for (int p=0;p<4;++p){
      int nr = ly + p*16, kc = lx*4;
      if (n0 + nr < N) {
        short4 o = make_short4(f2bf(tsh[nr][kc]), f2bf(tsh[nr][kc+1]),
                               f2bf(tsh[nr][kc+2]), f2bf(tsh[nr][kc+3]));
        *(short4*)(WT + (size_t)(rowoff+n0+nr)*384 + k0 + kc) = o;
      }
    }
  } else {
    int t = b - 373;
    int n0 = (t % 6)*64, k0 = (t/6)*64;
    int lx = threadIdx.x & 15, ly = threadIdx.x >> 4;
    #pragma unroll
    for (int p=0;p<4;++p){
      int r = ly + p*16, c = lx*4;
      float4 v = *(const float4*)(w_out + (size_t)(k0+r)*384 + n0 + c);
      tsh[c+0][r]=v.x; tsh[c+1][r]=v.y; tsh[c+2][r]=v.z; tsh[c+3][r]=v.w;
    }
    __syncthreads();
    #pragma unroll
    for (int p=0;p<4;++p){
      int nr = ly + p*16, kc = lx*4;
      short4 o = make_short4(f2bf(tsh[nr][kc]), f2bf(tsh[nr][kc+1]),
                             f2bf(tsh[nr][kc+2]), f2bf(tsh[nr][kc+3]));
      *(short4*)(w_outT + (size_t)(n0+nr)*2112 + k0 + kc) = o;
    }
  }
}

// ---------------- bf16 MFMA GEMM: C[M][N] = A[M][K] @ BT[N][K]^T ----------------
__global__ __launch_bounds__(256) void gemm_bf16_kernel(
    const short* __restrict__ A, const short* __restrict__ BT,
    float* __restrict__ C, const float* __restrict__ bias,
    int M, int N, int K)
{
  __shared__ __align__(16) short As[2][4096];
  __shared__ __align__(16) short Bs[2][4096];
  int tid = threadIdx.x;
  int n0 = blockIdx.x*128, m0 = blockIdx.y*128;
  int w = tid >> 6, lane = tid & 63;
  int wr = w >> 1, wc = w & 1;
  int lrow = lane & 15, kg = lane >> 4;
  int nt = K >> 5;
  f32x4 acc[4][4] = {};

  const short* Abase = A  + (size_t)m0*K;
  const short* Bbase = BT + (size_t)n0*K;
  int sr = tid >> 2, scc = (tid & 3)*8;

  auto stage = [&](int b, int k0){
    const short* Ab = Abase + k0;
    const short* Bb = Bbase + k0;
    gload16(Ab + (size_t)sr*K + scc,      &As[b][tid*8]);
    gload16(Bb + (size_t)sr*K + scc,      &Bs[b][tid*8]);
    gload16(Ab + (size_t)(sr+64)*K + scc, &As[b][2048 + tid*8]);
    gload16(Bb + (size_t)(sr+64)*K + scc, &Bs[b][2048 + tid*8]);
  };

  stage(0, 0);
  for (int kt = 0; kt < nt; ++kt){
    int cb = kt & 1;
    if (kt + 1 < nt){
      stage(cb ^ 1, (kt+1) << 5);
      asm volatile("s_waitcnt vmcnt(4)" ::: "memory");
    } else {
      asm volatile("s_waitcnt vmcnt(0)" ::: "memory");
    }
    __builtin_amdgcn_s_barrier();
    short8v af[4], bfr[4];
    #pragma unroll
    for (int mi=0; mi<4; ++mi)
      af[mi]  = *(const short8v*)&As[cb][(wr*64 + mi*16 + lrow)*32 + kg*8];
    #pragma unroll
    for (int ni=0; ni<4; ++ni)
      bfr[ni] = *(const short8v*)&Bs[cb][(wc*64 + ni*16 + lrow)*32 + kg*8];
    #pragma unroll
    for (int mi=0; mi<4; ++mi)
      #pragma unroll
      for (int ni=0; ni<4; ++ni)
        acc[mi][ni] = __builtin_amdgcn_mfma_f32_16x16x32_bf16(af[mi], bfr[ni], acc[mi][ni], 0, 0, 0);
    __builtin_amdgcn_s_barrier();
  }

  #pragma unroll
  for (int mi=0; mi<4; ++mi)
    #pragma unroll
    for (int ni=0; ni<4; ++ni) {
      int col = n0 + wc*64 + ni*16 + lrow;
      float bv = bias ? bias[col] : 0.f;
      #pragma unroll
      for (int jj=0; jj<4; ++jj) {
        int row = m0 + wr*64 + mi*16 + kg*4 + jj;
        C[(size_t)row*N + col] = acc[mi][ni][jj] + bv;
      }
    }
}

// ---------------- split-K GEMM: Cpart[z] = A[:, z*Kc:(z+1)*Kc] @ BT^T chunk ----------------
__global__ __launch_bounds__(256) void gemm_splitk_kernel(
    const short* __restrict__ A, const short* __restrict__ BT,
    float* __restrict__ Cpart, int M, int N, int lda, int Kc)
{
  __shared__ __align__(16) short As[2][4096];
  __shared__ __align__(16) short Bs[2][4096];
  int tid = threadIdx.x;
  int n0 = blockIdx.x*128, m0 = blockIdx.y*128;
  int kb = blockIdx.z;
  int w = tid >> 6, lane = tid & 63;
  int wr = w >> 1, wc = w & 1;
  int lrow = lane & 15, kg = lane >> 4;
  int nt = Kc >> 5;
  f32x4 acc[4][4] = {};

  const short* Abase = A  + (size_t)m0*lda + (size_t)kb*Kc;
  const short* Bbase = BT + (size_t)n0*lda + (size_t)kb*Kc;
  int sr = tid >> 2, scc = (tid & 3)*8;

  auto stage = [&](int b, int k0){
    const short* Ab = Abase + k0;
    const short* Bb = Bbase + k0;
    gload16(Ab + (size_t)sr*lda + scc,      &As[b][tid*8]);
    gload16(Bb + (size_t)sr*lda + scc,      &Bs[b][tid*8]);
    gload16(Ab + (size_t)(sr+64)*lda + scc, &As[b][2048 + tid*8]);
    gload16(Bb + (size_t)(sr+64)*lda + scc, &Bs[b][2048 + tid*8]);
  };

  stage(0, 0);
  for (int kt = 0; kt < nt; ++kt){
    int cb = kt & 1;
    if (kt + 1 < nt){
      stage(cb ^ 1, (kt+1) << 5);
      asm volatile("s_waitcnt vmcnt(4)" ::: "memory");
    } else {
      asm volatile("s_waitcnt vmcnt(0)" ::: "memory");
    }
    __builtin_amdgcn_s_barrier();
    short8v af[4], bfr[4];
    #pragma unroll
    for (int mi=0; mi<4; ++mi)
      af[mi]  = *(const short8v*)&As[cb][(wr*64 + mi*16 + lrow)*32 + kg*8];
    #pragma unroll
    for (int ni=0; ni<4; ++ni)
      bfr[ni] = *(const short8v*)&Bs[cb][(wc*64 + ni*16 + lrow)*32 + kg*8];
    #pragma unroll
    for (int mi=0; mi<4; ++mi)
      #pragma unroll
      for (int ni=0; ni<4; ++ni)
        acc[mi][ni] = __builtin_amdgcn_mfma_f32_16x16x32_bf16(af[mi], bfr[ni], acc[mi][ni], 0, 0, 0);
    __builtin_amdgcn_s_barrier();
  }

  float* Cp = Cpart + (size_t)kb*M*N;
  #pragma unroll
  for (int mi=0; mi<4; ++mi)
    #pragma unroll
    for (int ni=0; ni<4; ++ni) {
      int col = n0 + wc*64 + ni*16 + lrow;
      #pragma unroll
      for (int jj=0; jj<4; ++jj) {
        int row = m0 + wr*64 + mi*16 + kg*4 + jj;
        Cp[(size_t)row*N + col] = acc[mi][ni][jj];
      }
    }
}

// ---------------- reduce 6 split-K partials + bias ----------------
__global__ __launch_bounds__(256) void reduce6_kernel(
    const float* __restrict__ Cpart, const float* __restrict__ bias,
    float* __restrict__ out)
{
  int idx = blockIdx.x*256 + threadIdx.x;   // 196608 total
  float v = bias[idx % 384];
  #pragma unroll
  for (int zc = 0; zc < 6; ++zc) v += Cpart[(size_t)zc*196608 + idx];
  out[idx] = v;
}

// ---------------- transform: P -> kT, kpgT, qpg, vcatT (LDS-staged, coalesced) ----------------
__global__ __launch_bounds__(256) void transform_kernel(
    const float* __restrict__ P, const float* __restrict__ T,
    float* __restrict__ kT, float* __restrict__ kpgT,
    float* __restrict__ qpg, unsigned short* __restrict__ vcatT)
{
  __shared__ float Ps[8][1160];
  __shared__ float Ts[8][12];
  int tid = threadIdx.x;
  int j0 = blockIdx.x*8;
  for (int u = tid; u < 8*288; u += 256) {
    int r = u / 288, c4 = u % 288;
    *(float4*)&Ps[r][c4*4] = *(const float4*)(P + (size_t)(j0+r)*1152 + c4*4);
  }
  if (tid < 96) {
    int r = tid / 12, e = tid % 12;
    Ts[r][e] = (e < 9) ? T[(j0+r)*16 + (e/3)*4 + (e%3)]
                       : T[(j0+r)*16 + (e-9)*4 + 3];
  }
  __syncthreads();
  for (int u = tid; u < 1536; u += 256) {
    int row = u >> 3, jl = u & 7;
    kT[(size_t)row*512 + j0 + jl] = Ps[jl][192 + row];
  }
  for (int u = tid; u < 1152; u += 256) {
    int e = u >> 3, jl = u & 7;
    int x = e % 3, hp = e / 3;
    const float* R = &Ts[jl][0];
    float kx = Ps[jl][720+hp*3], ky = Ps[jl][720+hp*3+1], kz = Ps[jl][720+hp*3+2];
    kpgT[(size_t)e*512 + j0 + jl] = R[x*3]*kx + R[x*3+1]*ky + R[x*3+2]*kz + Ts[jl][9+x];
  }
  for (int u = tid; u < 1152; u += 256) {
    int jl = u / 144, e = u % 144;
    int x = e % 3, hp = e / 3;
    const float* R = &Ts[jl][0];
    float qx = Ps[jl][576+hp*3], qy = Ps[jl][576+hp*3+1], qz = Ps[jl][576+hp*3+2];
    qpg[(size_t)(j0+jl)*144 + e] = R[x*3]*qx + R[x*3+1]*qy + R[x*3+2]*qz + Ts[jl][9+x];
  }
  for (int u = tid; u < 3840; u += 256) {
    int d = u >> 3, jl = u & 7;
    float val;
    if (d < 192) val = Ps[jl][384 + d];
    else {
      int e = d - 192;
      int x = e % 3, hp = e / 3;
      const float* R = &Ts[jl][0];
      float vx = Ps[jl][864+hp*3], vy = Ps[jl][864+hp*3+1], vz = Ps[jl][864+hp*3+2];
      val = R[x*3]*vx + R[x*3+1]*vy + R[x*3+2]*vz + Ts[jl][9+x];
    }
    vcatT[(size_t)d*512 + j0 + jl] = (unsigned short)f2bf(val);
  }
}

// ---------------- attn partials: block = (i, jq), 128 j each; bias + o_pair MFMA ----------------
// part layout per block (stride 2048 f32):
//   [0:12) m, [12:24) S, [24:216) o, [216:504) opg, [512:2048) o_pair f32
__global__ __launch_bounds__(256) void attn_part_kernel(
    const float* __restrict__ P, const float* __restrict__ qpg,
    const float* __restrict__ kT, const float* __restrict__ kpgT,
    const short* __restrict__ wbbf, const float* __restrict__ z,
    const unsigned short* __restrict__ vcatT,
    const float* __restrict__ gamma, float* __restrict__ part)
{
  __shared__ short zbT[16384];                 // swizzled bf16 z^T [zc][j]
  __shared__ float sc[12][132];
  __shared__ float qrow[192], qpgrow[144], gsp[12];
  int bid = blockIdx.x;
  int i = bid >> 2, jq = bid & 3;
  int j0 = jq * 128;
  int tid = threadIdx.x;
  float* pb = part + (size_t)bid * 2048;
  const float* zslab = z + (size_t)i*65536 + (size_t)j0*128;  // [128 j][128 zc]

  if (tid < 192) qrow[tid] = P[(size_t)i*1152 + tid];
  if (tid < 144) qpgrow[tid] = qpg[(size_t)i*144 + tid];
  if (tid < 12)  { float g = gamma[tid]; gsp[tid] = log1pf(__expf(g)); }

  // P0a: stage zbT bf16 with 16B-chunk XOR swizzle (chunk ^= (zc&15)^(zc>>4))
  {
    int q = tid & 31, jb = tid >> 5;
    for (int r = 0; r < 16; ++r) {
      int jj = jb + r*8;
      float4 f = *(const float4*)(zslab + (size_t)jj*128 + q*4);
      short wv0 = f2bf(f.x), wv1 = f2bf(f.y), wv2 = f2bf(f.z), wv3 = f2bf(f.w);
      int jc = jj >> 3, jr = jj & 7;
      int zc = q*4;
      zbT[(zc+0)*128 + ((jc ^ (((zc+0)&15)^((zc+0)>>4))) << 3) + jr] = wv0;
      zbT[(zc+1)*128 + ((jc ^ (((zc+1)&15)^((zc+1)>>4))) << 3) + jr] = wv1;
      zbT[(zc+2)*128 + ((jc ^ (((zc+2)&15)^((zc+2)>>4))) << 3) + jr] = wv2;
      zbT[(zc+3)*128 + ((jc ^ (((zc+3)&15)^((zc+3)>>4))) << 3) + jr] = wv3;
    }
  }

  // P0b: bias via skinny MFMA — seed sc[h][j] with wL*(z@w_b)
  {
    int w = tid >> 6, lane = tid & 63;
    int lrow = lane & 15, kg = lane >> 4;
    #pragma unroll
    for (int sub = 0; sub < 2; ++sub) {
      int m = w*2 + sub;
      const float* zr = zslab + (size_t)(m*16 + lrow)*128;
      f32x4 acc = {0.f,0.f,0.f,0.f};
      #pragma unroll
      for (int ks = 0; ks < 4; ++ks) {
        int c0 = ks*32 + kg*8;
        float4 z0 = *(const float4*)(zr + c0);
        float4 z1 = *(const float4*)(zr + c0 + 4);
        short8v af;
        af[0]=f2bf(z0.x); af[1]=f2bf(z0.y); af[2]=f2bf(z0.z); af[3]=f2bf(z0.w);
        af[4]=f2bf(z1.x); af[5]=f2bf(z1.y); af[6]=f2bf(z1.z); af[7]=f2bf(z1.w);
        short8v bfv = *(const short8v*)(wbbf + lrow*128 + c0);
        acc = __builtin_amdgcn_mfma_f32_16x16x32_bf16(af, bfv, acc, 0, 0, 0);
      }
      if (lrow < 12) {
        #pragma unroll
        for (int r=0;r<4;++r)
          sc[lrow][m*16 + kg*4 + r] = acc[r];
      }
    }
  }
  __syncthreads();

  // P1: logits for 12 heads over this j-slice (sc pre-seeded with bias)
  {
    int j = tid & 127, hh = tid >> 7;
    const float wL = 0.57735026918962576f;
    const float wC = 0.23570226039551584f;
    #pragma unroll
    for (int hl = 0; hl < 6; ++hl) {
      int h = hh*6 + hl;
      float dot = 0.f;
      #pragma unroll
      for (int c=0;c<16;++c) dot += qrow[h*16+c] * kT[(size_t)(h*16+c)*512 + j0 + j];
      float d2 = 0.f;
      #pragma unroll
      for (int e=0;e<12;++e){ float d = qpgrow[h*12+e] - kpgT[(size_t)(h*12+e)*512 + j0 + j]; d2 += d*d; }
      sc[h][j] += wL*(dot*0.25f - 0.5f*gsp[h]*wC*d2);
    }
  }
  __syncthreads();

  // P2: partial softmax per head: local max m, unnormalized p, local sum S
  if (tid < 192) {
    int h = tid >> 4, l = tid & 15;
    float v[8]; float m = -1e30f;
    #pragma unroll
    for (int u=0;u<8;++u){ v[u] = sc[h][l + u*16]; m = fmaxf(m, v[u]); }
    #pragma unroll
    for (int s2=1;s2<16;s2<<=1) m = fmaxf(m, __shfl_xor(m, s2));
    float sum = 0.f;
    #pragma unroll
    for (int u=0;u<8;++u){ v[u] = __expf(v[u]-m); sum += v[u]; sc[h][l + u*16] = v[u]; }
    #pragma unroll
    for (int s2=1;s2<16;s2<<=1) sum += __shfl_xor(sum, s2);
    if (l == 0) { pb[h] = m; pb[12+h] = sum; }
  }
  __syncthreads();

  // P3: partial o (192) + opg (288) over vcatT j-slice
  if (tid < 240) {
    #pragma unroll
    for (int rr=0; rr<2; ++rr) {
      int d = tid + rr*240;
      int h = (d < 192) ? (d >> 4) : ((d - 192) / 24);
      const unsigned short* vp = vcatT + (size_t)d*512 + j0;
      float s = 0.f;
      #pragma unroll 4
      for (int jc = 0; jc < 16; ++jc) {
        short8v vv = *(const short8v*)(vp + jc*8);
        float4 a0 = *(const float4*)&sc[h][jc*8];
        float4 a1 = *(const float4*)&sc[h][jc*8+4];
        s += a0.x*bf2f((unsigned short)vv[0]) + a0.y*bf2f((unsigned short)vv[1])
           + a0.z*bf2f((unsigned short)vv[2]) + a0.w*bf2f((unsigned short)vv[3])
           + a1.x*bf2f((unsigned short)vv[4]) + a1.y*bf2f((unsigned short)vv[5])
           + a1.z*bf2f((unsigned short)vv[6]) + a1.w*bf2f((unsigned short)vv[7]);
      }
      pb[24 + d] = s;
    }
  }

  // P4: partial o_pair = sc @ z via MFMA (A = sc rows, B = zbT swizzled)
  {
    int w = tid >> 6, lane = tid & 63;
    int lrow = lane & 15, kg = lane >> 4;
    short8v afr[4];
    #pragma unroll
    for (int ks = 0; ks < 4; ++ks) {
      int row = lrow < 12 ? lrow : 11;
      const float* sp = &sc[row][ks*32 + kg*8];
      float4 a0 = *(const float4*)sp;
      float4 a1 = *(const float4*)(sp+4);
      short8v a;
      a[0]=f2bf(a0.x); a[1]=f2bf(a0.y); a[2]=f2bf(a0.z); a[3]=f2bf(a0.w);
      a[4]=f2bf(a1.x); a[5]=f2bf(a1.y); a[6]=f2bf(a1.z); a[7]=f2bf(a1.w);
      afr[ks] = a;
    }
    #pragma unroll
    for (int t = 0; t < 2; ++t) {
      int zc = w*32 + t*16 + lrow;
      int sw = (zc & 15) ^ (zc >> 4);
      f32x4 pacc = {0.f,0.f,0.f,0.f};
      #pragma unroll
      for (int ks = 0; ks < 4; ++ks) {
        int chunk = (ks*4 + kg) ^ sw;
        short8v bfv = *(const short8v*)&zbT[zc*128 + (chunk<<3)];
        pacc = __builtin_amdgcn_mfma_f32_16x16x32_bf16(afr[ks], bfv, pacc, 0, 0, 0);
      }
      if (kg < 3) {
        #pragma unroll
        for (int r = 0; r < 4; ++r) {
          int h = kg*4 + r;
          pb[512 + h*128 + zc] = pacc[r];
        }
      }
    }
  }
}

// ---------------- combine partials -> cat row ----------------
__global__ __launch_bounds__(256) void combine_kernel(
    const float* __restrict__ part, const float* __restrict__ T,
    short* __restrict__ cat)
{
  __shared__ float w4[4][12], inv[12];
  __shared__ float opgf[288];
  __shared__ float Ri[9], ti[3];
  int i = blockIdx.x, tid = threadIdx.x;
  const float* pb = part + (size_t)i * 4 * 2048;

  if (tid < 12) {
    float m0 = pb[tid], m1 = pb[2048+tid], m2 = pb[4096+tid], m3 = pb[6144+tid];
    float mh = fmaxf(fmaxf(m0,m1), fmaxf(m2,m3));
    float w0 = __expf(m0-mh), w1 = __expf(m1-mh), w2 = __expf(m2-mh), w3 = __expf(m3-mh);
    float S = w0*pb[12+tid] + w1*pb[2060+tid] + w2*pb[4108+tid] + w3*pb[6156+tid];
    w4[0][tid]=w0; w4[1][tid]=w1; w4[2][tid]=w2; w4[3][tid]=w3;
    inv[tid] = 1.f/S;
  }
  if (tid >= 64 && tid < 73) { int e = tid-64; Ri[e] = T[i*16 + (e/3)*4 + (e%3)]; }
  if (tid >= 76 && tid < 79) { int e = tid-76; ti[e] = T[i*16 + e*4 + 3]; }
  __syncthreads();

  short* crow = cat + (size_t)i*2112;

  if (tid < 192) {
    int h = tid >> 4;
    float v = w4[0][h]*pb[24+tid] + w4[1][h]*pb[2072+tid]
            + w4[2][h]*pb[4120+tid] + w4[3][h]*pb[6168+tid];
    crow[tid] = f2bf(v * inv[h]);
  }
  for (int u = tid; u < 288; u += 256) {
    int h = u / 24;
    float v = w4[0][h]*pb[216+u] + w4[1][h]*pb[2264+u]
            + w4[2][h]*pb[4312+u] + w4[3][h]*pb[6360+u];
    opgf[u] = v * inv[h];
  }
  __syncthreads();
  if (tid < 96) {
    float d0 = opgf[tid*3+0]-ti[0], d1 = opgf[tid*3+1]-ti[1], d2v = opgf[tid*3+2]-ti[2];
    float o0 = Ri[0]*d0 + Ri[3]*d1 + Ri[6]*d2v;
    float o1 = Ri[1]*d0 + Ri[4]*d1 + Ri[7]*d2v;
    float o2 = Ri[2]*d0 + Ri[5]*d1 + Ri[8]*d2v;
    crow[192+tid*3+0] = f2bf(o0); crow[192+tid*3+1] = f2bf(o1); crow[192+tid*3+2] = f2bf(o2);
    crow[480+tid] = f2bf(sqrtf(o0*o0 + o1*o1 + o2*o2 + 1e-8f));
  }
  for (int u = tid; u < 1536; u += 256) {
    int h = u >> 7;
    float v = w4[0][h]*pb[512+u] + w4[1][h]*pb[2560+u]
            + w4[2][h]*pb[4608+u] + w4[3][h]*pb[6656+u];
    crow[576+u] = f2bf(v * inv[h]);
  }
}

// ---------------- launch ----------------
extern "C" void kernel_launch(void* const* d_in, const int* in_sizes, int n_in,
                              void* d_out, int out_size, void* d_ws, size_t ws_size,
                              hipStream_t stream) {
  const float* s     = (const float*)d_in[0];
  const float* z     = (const float*)d_in[1];
  const float* T     = (const float*)d_in[2];
  const float* w_q   = (const float*)d_in[3];
  const float* w_k   = (const float*)d_in[4];
  const float* w_v   = (const float*)d_in[5];
  const float* w_qp  = (const float*)d_in[6];
  const float* w_kp  = (const float*)d_in[7];
  const float* w_vp  = (const float*)d_in[8];
  const float* w_b   = (const float*)d_in[9];
  const float* gamma = (const float*)d_in[10];
  const float* w_out = (const float*)d_in[11];
  const float* b_out = (const float*)d_in[12];

  float* ws = (float*)d_ws;
  float* P      = ws;                        // 589824
  float* kT     = ws + 589824;               // 98304
  float* kpgT   = ws + 688128;               // 73728
  float* qpg    = ws + 761856;               // 73728
  short* wbbf   = (short*)(ws + 835584);     // 2048 sh (1024 f)
  short* s_bf   = (short*)(ws + 836608);     // 196608 sh (98304 f)
  short* WT     = (short*)(ws + 934912);     // 442368 sh (221184 f)
  short* w_outT = (short*)(ws + 1156096);    // 811008 sh (405504 f)
  unsigned short* vcatT = (unsigned short*)(ws + 1561600); // 245760 sh (122880 f)
  short* cat    = (short*)(ws + 1684480);    // 1081344 sh (540672 f)
  float* partb  = ws + 2225152;              // 2048*2048 = 4194304 f
  float* Cpart  = ws + 6419456;              // 6*196608 = 1179648 f

  prep_kernel<<<571, 256, 0, stream>>>(s, w_b, w_q, w_k, w_v, w_qp, w_kp, w_vp, w_out,
                                       s_bf, wbbf, WT, w_outT);
  gemm_bf16_kernel<<<dim3(9,4), 256, 0, stream>>>(s_bf, WT, P, nullptr, 512, 1152, 384);
  transform_kernel<<<64, 256, 0, stream>>>(P, T, kT, kpgT, qpg, vcatT);
  attn_part_kernel<<<2048, 256, 0, stream>>>(P, qpg, kT, kpgT, wbbf, z, vcatT, gamma, partb);
  combine_kernel<<<512, 256, 0, stream>>>(partb, T, cat);
  gemm_splitk_kernel<<<dim3(3,4,6), 256, 0, stream>>>(cat, w_outT, Cpart, 512, 384, 2112, 352);
  reduce6_kernel<<<768, 256, 0, stream>>>(Cpart, b_out, (float*)d_out);
}

// Round 18
// 105.648 us; speedup vs baseline: 1.3978x; 1.1074x over previous
//
#include <hip/hip_runtime.h>
#include <hip/hip_bf16.h>

typedef __attribute__((ext_vector_type(8))) short short8v;
typedef __attribute__((ext_vector_type(4))) float f32x4;

__device__ __forceinline__ short f2bf(float f){
  unsigned u = __builtin_bit_cast(unsigned, f);
  u += 0x7fffu + ((u >> 16) & 1u);
  return (short)(u >> 16);
}
__device__ __forceinline__ float bf2f(unsigned short s){
  unsigned u = ((unsigned)s) << 16;
  return __builtin_bit_cast(float, u);
}

__device__ __forceinline__ void gload16(const short* g, short* l){
  __builtin_amdgcn_global_load_lds(
    (const __attribute__((address_space(1))) unsigned int*)g,
    (__attribute__((address_space(3))) unsigned int*)l,
    16, 0, 0);
}

// ---------------- fused prep: cast s, wbbf table, both weight transposes ----------------
__global__ __launch_bounds__(256) void prep_kernel(
    const float* __restrict__ s, const float* __restrict__ w_b,
    const float* __restrict__ wq, const float* __restrict__ wk, const float* __restrict__ wv,
    const float* __restrict__ wqp, const float* __restrict__ wkp, const float* __restrict__ wvp,
    const float* __restrict__ w_out,
    short* __restrict__ s_bf, short* __restrict__ wbbf,
    short* __restrict__ WT, short* __restrict__ w_outT)
{
  __shared__ float tsh[64][65];
  int b = blockIdx.x;
  if (b < 192) {
    int gid = b*256 + threadIdx.x;
    float4 f = *(const float4*)(s + (size_t)gid*4);
    short4 o = make_short4(f2bf(f.x), f2bf(f.y), f2bf(f.z), f2bf(f.w));
    *(short4*)(s_bf + (size_t)gid*4) = o;
  } else if (b == 192) {
    const float wL = 0.57735026918962576f;
    for (int u = threadIdx.x; u < 2048; u += 256) {
      int h = u >> 7, zc = u & 127;
      float v = (h < 12) ? w_b[zc*12 + h]*wL : 0.f;
      wbbf[u] = f2bf(v);
    }
  } else if (b < 373) {
    int t = b - 193;
    int n0 = (t % 5)*64, k0 = ((t/5) % 6)*64, src = t/30;
    const float* in; int N; int rowoff;
    switch (src) {
      case 0: in = wq;  N = 192; rowoff = 0;   break;
      case 1: in = wk;  N = 192; rowoff = 192; break;
      case 2: in = wv;  N = 192; rowoff = 384; break;
      case 3: in = wqp; N = 144; rowoff = 576; break;
      case 4: in = wkp; N = 144; rowoff = 720; break;
      default:in = wvp; N = 288; rowoff = 864; break;
    }
    if (n0 >= N) return;
    int lx = threadIdx.x & 15, ly = threadIdx.x >> 4;
    #pragma unroll
    for (int p=0;p<4;++p){
      int r = ly + p*16, c = lx*4;
      float v0=0.f,v1=0.f,v2=0.f,v3=0.f;
      if (n0 + c + 3 < N) {
        float4 v = *(const float4*)(in + (size_t)(k0+r)*N + n0 + c);
        v0=v.x; v1=v.y; v2=v.z; v3=v.w;
      } else {
        if (n0+c+0 < N) v0 = in[(size_t)(k0+r)*N + n0+c+0];
        if (n0+c+1 < N) v1 = in[(size_t)(k0+r)*N + n0+c+1];
        if (n0+c+2 < N) v2 = in[(size_t)(k0+r)*N + n0+c+2];
        if (n0+c+3 < N) v3 = in[(size_t)(k0+r)*N + n0+c+3];
      }
      tsh[c+0][r]=v0; tsh[c+1][r]=v1; tsh[c+2][r]=v2; tsh[c+3][r]=v3;
    }
    __syncthreads();
    #pragma unroll
    for (int p=0;p<4;++p){
      int nr = ly + p*16, kc = lx*4;
      if (n0 + nr < N) {
        short4 o = make_short4(f2bf(tsh[nr][kc]), f2bf(tsh[nr][kc+1]),
                               f2bf(tsh[nr][kc+2]), f2bf(tsh[nr][kc+3]));
        *(short4*)(WT + (size_t)(rowoff+n0+nr)*384 + k0 + kc) = o;
      }
    }
  } else {
    int t = b - 373;
    int n0 = (t % 6)*64, k0 = (t/6)*64;
    int lx = threadIdx.x & 15, ly = threadIdx.x >> 4;
    #pragma unroll
    for (int p=0;p<4;++p){
      int r = ly + p*16, c = lx*4;
      float4 v = *(const float4*)(w_out + (size_t)(k0+r)*384 + n0 + c);
      tsh[c+0][r]=v.x; tsh[c+1][r]=v.y; tsh[c+2][r]=v.z; tsh[c+3][r]=v.w;
    }
    __syncthreads();
    #pragma unroll
    for (int p=0;p<4;++p){
      int nr = ly + p*16, kc = lx*4;
      short4 o = make_short4(f2bf(tsh[nr][kc]), f2bf(tsh[nr][kc+1]),
                             f2bf(tsh[nr][kc+2]), f2bf(tsh[nr][kc+3]));
      *(short4*)(w_outT + (size_t)(n0+nr)*2112 + k0 + kc) = o;
    }
  }
}

// ---------------- bf16 MFMA GEMM: C[M][N] = A[M][K] @ BT[N][K]^T ----------------
__global__ __launch_bounds__(256) void gemm_bf16_kernel(
    const short* __restrict__ A, const short* __restrict__ BT,
    float* __restrict__ C, const float* __restrict__ bias,
    int M, int N, int K)
{
  __shared__ __align__(16) short As[2][4096];
  __shared__ __align__(16) short Bs[2][4096];
  int tid = threadIdx.x;
  int n0 = blockIdx.x*128, m0 = blockIdx.y*128;
  int w = tid >> 6, lane = tid & 63;
  int wr = w >> 1, wc = w & 1;
  int lrow = lane & 15, kg = lane >> 4;
  int nt = K >> 5;
  f32x4 acc[4][4] = {};

  const short* Abase = A  + (size_t)m0*K;
  const short* Bbase = BT + (size_t)n0*K;
  int sr = tid >> 2, scc = (tid & 3)*8;

  auto stage = [&](int b, int k0){
    const short* Ab = Abase + k0;
    const short* Bb = Bbase + k0;
    gload16(Ab + (size_t)sr*K + scc,      &As[b][tid*8]);
    gload16(Bb + (size_t)sr*K + scc,      &Bs[b][tid*8]);
    gload16(Ab + (size_t)(sr+64)*K + scc, &As[b][2048 + tid*8]);
    gload16(Bb + (size_t)(sr+64)*K + scc, &Bs[b][2048 + tid*8]);
  };

  stage(0, 0);
  for (int kt = 0; kt < nt; ++kt){
    int cb = kt & 1;
    if (kt + 1 < nt){
      stage(cb ^ 1, (kt+1) << 5);
      asm volatile("s_waitcnt vmcnt(4)" ::: "memory");
    } else {
      asm volatile("s_waitcnt vmcnt(0)" ::: "memory");
    }
    __builtin_amdgcn_s_barrier();
    short8v af[4], bfr[4];
    #pragma unroll
    for (int mi=0; mi<4; ++mi)
      af[mi]  = *(const short8v*)&As[cb][(wr*64 + mi*16 + lrow)*32 + kg*8];
    #pragma unroll
    for (int ni=0; ni<4; ++ni)
      bfr[ni] = *(const short8v*)&Bs[cb][(wc*64 + ni*16 + lrow)*32 + kg*8];
    #pragma unroll
    for (int mi=0; mi<4; ++mi)
      #pragma unroll
      for (int ni=0; ni<4; ++ni)
        acc[mi][ni] = __builtin_amdgcn_mfma_f32_16x16x32_bf16(af[mi], bfr[ni], acc[mi][ni], 0, 0, 0);
    __builtin_amdgcn_s_barrier();
  }

  #pragma unroll
  for (int mi=0; mi<4; ++mi)
    #pragma unroll
    for (int ni=0; ni<4; ++ni) {
      int col = n0 + wc*64 + ni*16 + lrow;
      float bv = bias ? bias[col] : 0.f;
      #pragma unroll
      for (int jj=0; jj<4; ++jj) {
        int row = m0 + wr*64 + mi*16 + kg*4 + jj;
        C[(size_t)row*N + col] = acc[mi][ni][jj] + bv;
      }
    }
}

// ---------------- split-K GEMM ----------------
__global__ __launch_bounds__(256) void gemm_splitk_kernel(
    const short* __restrict__ A, const short* __restrict__ BT,
    float* __restrict__ Cpart, int M, int N, int lda, int Kc)
{
  __shared__ __align__(16) short As[2][4096];
  __shared__ __align__(16) short Bs[2][4096];
  int tid = threadIdx.x;
  int n0 = blockIdx.x*128, m0 = blockIdx.y*128;
  int kb = blockIdx.z;
  int w = tid >> 6, lane = tid & 63;
  int wr = w >> 1, wc = w & 1;
  int lrow = lane & 15, kg = lane >> 4;
  int nt = Kc >> 5;
  f32x4 acc[4][4] = {};

  const short* Abase = A  + (size_t)m0*lda + (size_t)kb*Kc;
  const short* Bbase = BT + (size_t)n0*lda + (size_t)kb*Kc;
  int sr = tid >> 2, scc = (tid & 3)*8;

  auto stage = [&](int b, int k0){
    const short* Ab = Abase + k0;
    const short* Bb = Bbase + k0;
    gload16(Ab + (size_t)sr*lda + scc,      &As[b][tid*8]);
    gload16(Bb + (size_t)sr*lda + scc,      &Bs[b][tid*8]);
    gload16(Ab + (size_t)(sr+64)*lda + scc, &As[b][2048 + tid*8]);
    gload16(Bb + (size_t)(sr+64)*lda + scc, &Bs[b][2048 + tid*8]);
  };

  stage(0, 0);
  for (int kt = 0; kt < nt; ++kt){
    int cb = kt & 1;
    if (kt + 1 < nt){
      stage(cb ^ 1, (kt+1) << 5);
      asm volatile("s_waitcnt vmcnt(4)" ::: "memory");
    } else {
      asm volatile("s_waitcnt vmcnt(0)" ::: "memory");
    }
    __builtin_amdgcn_s_barrier();
    short8v af[4], bfr[4];
    #pragma unroll
    for (int mi=0; mi<4; ++mi)
      af[mi]  = *(const short8v*)&As[cb][(wr*64 + mi*16 + lrow)*32 + kg*8];
    #pragma unroll
    for (int ni=0; ni<4; ++ni)
      bfr[ni] = *(const short8v*)&Bs[cb][(wc*64 + ni*16 + lrow)*32 + kg*8];
    #pragma unroll
    for (int mi=0; mi<4; ++mi)
      #pragma unroll
      for (int ni=0; ni<4; ++ni)
        acc[mi][ni] = __builtin_amdgcn_mfma_f32_16x16x32_bf16(af[mi], bfr[ni], acc[mi][ni], 0, 0, 0);
    __builtin_amdgcn_s_barrier();
  }

  float* Cp = Cpart + (size_t)kb*M*N;
  #pragma unroll
  for (int mi=0; mi<4; ++mi)
    #pragma unroll
    for (int ni=0; ni<4; ++ni) {
      int col = n0 + wc*64 + ni*16 + lrow;
      #pragma unroll
      for (int jj=0; jj<4; ++jj) {
        int row = m0 + wr*64 + mi*16 + kg*4 + jj;
        Cp[(size_t)row*N + col] = acc[mi][ni][jj];
      }
    }
}

// ---------------- reduce 6 split-K partials + bias ----------------
__global__ __launch_bounds__(256) void reduce6_kernel(
    const float* __restrict__ Cpart, const float* __restrict__ bias,
    float* __restrict__ out)
{
  int idx = blockIdx.x*256 + threadIdx.x;   // 196608 total
  float v = bias[idx % 384];
  #pragma unroll
  for (int zc = 0; zc < 6; ++zc) v += Cpart[(size_t)zc*196608 + idx];
  out[idx] = v;
}

// ---------------- transform: P -> kT, kpgT, qpg, vcatH (j-major, head-chunked d) ----------------
// vcatH[j][512] bf16: chunk h = [40h,40h+40): 16 o values then 24 opg values; cols 480..511 zero
__global__ __launch_bounds__(256) void transform_kernel(
    const float* __restrict__ P, const float* __restrict__ T,
    float* __restrict__ kT, float* __restrict__ kpgT,
    float* __restrict__ qpg, unsigned short* __restrict__ vcatH)
{
  __shared__ float Ps[8][1160];
  __shared__ float Ts[8][12];
  int tid = threadIdx.x;
  int j0 = blockIdx.x*8;
  for (int u = tid; u < 8*288; u += 256) {
    int r = u / 288, c4 = u % 288;
    *(float4*)&Ps[r][c4*4] = *(const float4*)(P + (size_t)(j0+r)*1152 + c4*4);
  }
  if (tid < 96) {
    int r = tid / 12, e = tid % 12;
    Ts[r][e] = (e < 9) ? T[(j0+r)*16 + (e/3)*4 + (e%3)]
                       : T[(j0+r)*16 + (e-9)*4 + 3];
  }
  __syncthreads();
  for (int u = tid; u < 1536; u += 256) {
    int row = u >> 3, jl = u & 7;
    kT[(size_t)row*512 + j0 + jl] = Ps[jl][192 + row];
  }
  for (int u = tid; u < 1152; u += 256) {
    int e = u >> 3, jl = u & 7;
    int x = e % 3, hp = e / 3;
    const float* R = &Ts[jl][0];
    float kx = Ps[jl][720+hp*3], ky = Ps[jl][720+hp*3+1], kz = Ps[jl][720+hp*3+2];
    kpgT[(size_t)e*512 + j0 + jl] = R[x*3]*kx + R[x*3+1]*ky + R[x*3+2]*kz + Ts[jl][9+x];
  }
  for (int u = tid; u < 1152; u += 256) {
    int jl = u / 144, e = u % 144;
    int x = e % 3, hp = e / 3;
    const float* R = &Ts[jl][0];
    float qx = Ps[jl][576+hp*3], qy = Ps[jl][576+hp*3+1], qz = Ps[jl][576+hp*3+2];
    qpg[(size_t)(j0+jl)*144 + e] = R[x*3]*qx + R[x*3+1]*qy + R[x*3+2]*qz + Ts[jl][9+x];
  }
  // vcatH: per (jl, chunk-index)
  for (int u = tid; u < 4096; u += 256) {
    int jl = u >> 9, dn = u & 511;
    float val = 0.f;
    if (dn < 480) {
      int h = dn / 40, c = dn % 40;
      if (c < 16) {
        val = Ps[jl][384 + h*16 + c];              // v
      } else {
        int e = c - 16;                             // 0..23 within head
        int x = e % 3, hp = e / 3;
        const float* R = &Ts[jl][0];
        float vx = Ps[jl][864+h*24+hp*3], vy = Ps[jl][864+h*24+hp*3+1], vz = Ps[jl][864+h*24+hp*3+2];
        val = R[x*3]*vx + R[x*3+1]*vy + R[x*3+2]*vz + Ts[jl][9+x];
      }
    }
    vcatH[(size_t)(j0+jl)*512 + dn] = (unsigned short)f2bf(val);
  }
}

// ---------------- attn partials: block = (i, jq), 128 j each ----------------
// part layout per block (stride 2048 f32):
//   [0:12) m, [12:24) S, [24:504) o+opg in HEAD-CHUNK order (40h+c), [512:2048) o_pair f32
__global__ __launch_bounds__(256) void attn_part_kernel(
    const float* __restrict__ P, const float* __restrict__ qpg,
    const float* __restrict__ kT, const float* __restrict__ kpgT,
    const short* __restrict__ wbbf, const float* __restrict__ z,
    const unsigned short* __restrict__ vcatH,
    const float* __restrict__ gamma, float* __restrict__ part)
{
  __shared__ short zbT[16384];                 // swizzled bf16 z^T [zc][j]
  __shared__ float sc[12][132];
  __shared__ float ppart[4][512];
  __shared__ float qrow[192], qpgrow[144], gsp[12];
  int bid = blockIdx.x;
  int i = bid >> 2, jq = bid & 3;
  int j0 = jq * 128;
  int tid = threadIdx.x;
  float* pb = part + (size_t)bid * 2048;
  const float* zslab = z + (size_t)i*65536 + (size_t)j0*128;  // [128 j][128 zc]

  if (tid < 192) qrow[tid] = P[(size_t)i*1152 + tid];
  if (tid < 144) qpgrow[tid] = qpg[(size_t)i*144 + tid];
  if (tid < 12)  { float g = gamma[tid]; gsp[tid] = log1pf(__expf(g)); }

  // P0a: stage zbT bf16 with 16B-chunk XOR swizzle (chunk ^= (zc&15)^(zc>>4))
  {
    int q = tid & 31, jb = tid >> 5;
    for (int r = 0; r < 16; ++r) {
      int jj = jb + r*8;
      float4 f = *(const float4*)(zslab + (size_t)jj*128 + q*4);
      short wv0 = f2bf(f.x), wv1 = f2bf(f.y), wv2 = f2bf(f.z), wv3 = f2bf(f.w);
      int jc = jj >> 3, jr = jj & 7;
      int zc = q*4;
      zbT[(zc+0)*128 + ((jc ^ (((zc+0)&15)^((zc+0)>>4))) << 3) + jr] = wv0;
      zbT[(zc+1)*128 + ((jc ^ (((zc+1)&15)^((zc+1)>>4))) << 3) + jr] = wv1;
      zbT[(zc+2)*128 + ((jc ^ (((zc+2)&15)^((zc+2)>>4))) << 3) + jr] = wv2;
      zbT[(zc+3)*128 + ((jc ^ (((zc+3)&15)^((zc+3)>>4))) << 3) + jr] = wv3;
    }
  }

  // P0b: bias via skinny MFMA — seed sc[h][j] with wL*(z@w_b)
  {
    int w = tid >> 6, lane = tid & 63;
    int lrow = lane & 15, kg = lane >> 4;
    #pragma unroll
    for (int sub = 0; sub < 2; ++sub) {
      int m = w*2 + sub;
      const float* zr = zslab + (size_t)(m*16 + lrow)*128;
      f32x4 acc = {0.f,0.f,0.f,0.f};
      #pragma unroll
      for (int ks = 0; ks < 4; ++ks) {
        int c0 = ks*32 + kg*8;
        float4 z0 = *(const float4*)(zr + c0);
        float4 z1 = *(const float4*)(zr + c0 + 4);
        short8v af;
        af[0]=f2bf(z0.x); af[1]=f2bf(z0.y); af[2]=f2bf(z0.z); af[3]=f2bf(z0.w);
        af[4]=f2bf(z1.x); af[5]=f2bf(z1.y); af[6]=f2bf(z1.z); af[7]=f2bf(z1.w);
        short8v bfv = *(const short8v*)(wbbf + lrow*128 + c0);
        acc = __builtin_amdgcn_mfma_f32_16x16x32_bf16(af, bfv, acc, 0, 0, 0);
      }
      if (lrow < 12) {
        #pragma unroll
        for (int r=0;r<4;++r)
          sc[lrow][m*16 + kg*4 + r] = acc[r];
      }
    }
  }
  __syncthreads();

  // P1: logits for 12 heads over this j-slice (sc pre-seeded with bias)
  {
    int j = tid & 127, hh = tid >> 7;
    const float wL = 0.57735026918962576f;
    const float wC = 0.23570226039551584f;
    #pragma unroll
    for (int hl = 0; hl < 6; ++hl) {
      int h = hh*6 + hl;
      float dot = 0.f;
      #pragma unroll
      for (int c=0;c<16;++c) dot += qrow[h*16+c] * kT[(size_t)(h*16+c)*512 + j0 + j];
      float d2 = 0.f;
      #pragma unroll
      for (int e=0;e<12;++e){ float d = qpgrow[h*12+e] - kpgT[(size_t)(h*12+e)*512 + j0 + j]; d2 += d*d; }
      sc[h][j] += wL*(dot*0.25f - 0.5f*gsp[h]*wC*d2);
    }
  }
  __syncthreads();

  // P2: partial softmax per head: local max m, unnormalized p, local sum S
  if (tid < 192) {
    int h = tid >> 4, l = tid & 15;
    float v[8]; float m = -1e30f;
    #pragma unroll
    for (int u=0;u<8;++u){ v[u] = sc[h][l + u*16]; m = fmaxf(m, v[u]); }
    #pragma unroll
    for (int s2=1;s2<16;s2<<=1) m = fmaxf(m, __shfl_xor(m, s2));
    float sum = 0.f;
    #pragma unroll
    for (int u=0;u<8;++u){ v[u] = __expf(v[u]-m); sum += v[u]; sc[h][l + u*16] = v[u]; }
    #pragma unroll
    for (int s2=1;s2<16;s2<<=1) sum += __shfl_xor(sum, s2);
    if (l == 0) { pb[h] = m; pb[12+h] = sum; }
  }
  __syncthreads();

  // P3: o+opg via vcatH — lane L owns d=8L..8L+7 (one head chunk), wave w owns 32 j.
  // One b128 per j (8 lines/instr), one broadcast ds_read, 8 FMAs.
  {
    int w = tid >> 6, lane = tid & 63;
    int hc = (lane < 60) ? (lane / 5) : 11;
    float acc[8] = {};
    const unsigned short* base = vcatH + (size_t)(j0 + w*32)*512 + lane*8;
    #pragma unroll 4
    for (int jj = 0; jj < 32; ++jj) {
      short8v vv = *(const short8v*)(base + (size_t)jj*512);
      float a = sc[hc][w*32 + jj];
      #pragma unroll
      for (int e=0;e<8;++e) acc[e] += a * bf2f((unsigned short)vv[e]);
    }
    #pragma unroll
    for (int e=0;e<8;++e) ppart[w][lane*8+e] = acc[e];
  }

  // P4: partial o_pair = sc @ z via MFMA (A = sc rows, B = zbT swizzled)
  {
    int w = tid >> 6, lane = tid & 63;
    int lrow = lane & 15, kg = lane >> 4;
    short8v afr[4];
    #pragma unroll
    for (int ks = 0; ks < 4; ++ks) {
      int row = lrow < 12 ? lrow : 11;
      const float* sp = &sc[row][ks*32 + kg*8];
      float4 a0 = *(const float4*)sp;
      float4 a1 = *(const float4*)(sp+4);
      short8v a;
      a[0]=f2bf(a0.x); a[1]=f2bf(a0.y); a[2]=f2bf(a0.z); a[3]=f2bf(a0.w);
      a[4]=f2bf(a1.x); a[5]=f2bf(a1.y); a[6]=f2bf(a1.z); a[7]=f2bf(a1.w);
      afr[ks] = a;
    }
    #pragma unroll
    for (int t = 0; t < 2; ++t) {
      int zc = w*32 + t*16 + lrow;
      int sw = (zc & 15) ^ (zc >> 4);
      f32x4 pacc = {0.f,0.f,0.f,0.f};
      #pragma unroll
      for (int ks = 0; ks < 4; ++ks) {
        int chunk = (ks*4 + kg) ^ sw;
        short8v bfv = *(const short8v*)&zbT[zc*128 + (chunk<<3)];
        pacc = __builtin_amdgcn_mfma_f32_16x16x32_bf16(afr[ks], bfv, pacc, 0, 0, 0);
      }
      if (kg < 3) {
        #pragma unroll
        for (int r = 0; r < 4; ++r) {
          int h = kg*4 + r;
          pb[512 + h*128 + zc] = pacc[r];
        }
      }
    }
  }
  __syncthreads();

  // reduce 4 wave-partials of P3 (head-chunk d order)
  if (tid < 240) {
    #pragma unroll
    for (int rr=0; rr<2; ++rr) {
      int d = tid + rr*240;
      pb[24 + d] = ppart[0][d] + ppart[1][d] + ppart[2][d] + ppart[3][d];
    }
  }
}

// ---------------- combine partials -> cat row (head-chunk o/opg order) ----------------
__global__ __launch_bounds__(256) void combine_kernel(
    const float* __restrict__ part, const float* __restrict__ T,
    short* __restrict__ cat)
{
  __shared__ float w4[4][12], inv[12];
  __shared__ float opgf[288];
  __shared__ float Ri[9], ti[3];
  int i = blockIdx.x, tid = threadIdx.x;
  const float* pb = part + (size_t)i * 4 * 2048;

  if (tid < 12) {
    float m0 = pb[tid], m1 = pb[2048+tid], m2 = pb[4096+tid], m3 = pb[6144+tid];
    float mh = fmaxf(fmaxf(m0,m1), fmaxf(m2,m3));
    float w0 = __expf(m0-mh), w1 = __expf(m1-mh), w2 = __expf(m2-mh), w3 = __expf(m3-mh);
    float S = w0*pb[12+tid] + w1*pb[2060+tid] + w2*pb[4108+tid] + w3*pb[6156+tid];
    w4[0][tid]=w0; w4[1][tid]=w1; w4[2][tid]=w2; w4[3][tid]=w3;
    inv[tid] = 1.f/S;
  }
  if (tid >= 64 && tid < 73) { int e = tid-64; Ri[e] = T[i*16 + (e/3)*4 + (e%3)]; }
  if (tid >= 76 && tid < 79) { int e = tid-76; ti[e] = T[i*16 + e*4 + 3]; }
  __syncthreads();

  short* crow = cat + (size_t)i*2112;

  if (tid < 192) {
    int h = tid >> 4, c = tid & 15;
    int dn = 40*h + c;
    float v = w4[0][h]*pb[24+dn] + w4[1][h]*pb[2072+dn]
            + w4[2][h]*pb[4120+dn] + w4[3][h]*pb[6168+dn];
    crow[tid] = f2bf(v * inv[h]);
  }
  for (int u = tid; u < 288; u += 256) {
    int h = u / 24, e = u % 24;
    int dn = 40*h + 16 + e;
    float v = w4[0][h]*pb[24+dn] + w4[1][h]*pb[2072+dn]
            + w4[2][h]*pb[4120+dn] + w4[3][h]*pb[6168+dn];
    opgf[u] = v * inv[h];
  }
  __syncthreads();
  if (tid < 96) {
    float d0 = opgf[tid*3+0]-ti[0], d1 = opgf[tid*3+1]-ti[1], d2v = opgf[tid*3+2]-ti[2];
    float o0 = Ri[0]*d0 + Ri[3]*d1 + Ri[6]*d2v;
    float o1 = Ri[1]*d0 + Ri[4]*d1 + Ri[7]*d2v;
    float o2 = Ri[2]*d0 + Ri[5]*d1 + Ri[8]*d2v;
    crow[192+tid*3+0] = f2bf(o0); crow[192+tid*3+1] = f2bf(o1); crow[192+tid*3+2] = f2bf(o2);
    crow[480+tid] = f2bf(sqrtf(o0*o0 + o1*o1 + o2*o2 + 1e-8f));
  }
  for (int u = tid; u < 1536; u += 256) {
    int h = u >> 7;
    float v = w4[0][h]*pb[512+u] + w4[1][h]*pb[2560+u]
            + w4[2][h]*pb[4608+u] + w4[3][h]*pb[6656+u];
    crow[576+u] = f2bf(v * inv[h]);
  }
}

// ---------------- launch ----------------
extern "C" void kernel_launch(void* const* d_in, const int* in_sizes, int n_in,
                              void* d_out, int out_size, void* d_ws, size_t ws_size,
                              hipStream_t stream) {
  const float* s     = (const float*)d_in[0];
  const float* z     = (const float*)d_in[1];
  const float* T     = (const float*)d_in[2];
  const float* w_q   = (const float*)d_in[3];
  const float* w_k   = (const float*)d_in[4];
  const float* w_v   = (const float*)d_in[5];
  const float* w_qp  = (const float*)d_in[6];
  const float* w_kp  = (const float*)d_in[7];
  const float* w_vp  = (const float*)d_in[8];
  const float* w_b   = (const float*)d_in[9];
  const float* gamma = (const float*)d_in[10];
  const float* w_out = (const float*)d_in[11];
  const float* b_out = (const float*)d_in[12];

  float* ws = (float*)d_ws;
  float* P      = ws;                        // 589824
  float* kT     = ws + 589824;               // 98304
  float* kpgT   = ws + 688128;               // 73728
  float* qpg    = ws + 761856;               // 73728
  short* wbbf   = (short*)(ws + 835584);     // 2048 sh (1024 f)
  short* s_bf   = (short*)(ws + 836608);     // 196608 sh (98304 f)
  short* WT     = (short*)(ws + 934912);     // 442368 sh (221184 f)
  short* w_outT = (short*)(ws + 1156096);    // 811008 sh (405504 f)
  unsigned short* vcatH = (unsigned short*)(ws + 1561600); // 262144 sh (131072 f)
  short* cat    = (short*)(ws + 1692672);    // 1081344 sh (540672 f)
  float* partb  = ws + 2233344;              // 2048*2048 = 4194304 f
  float* Cpart  = ws + 6427648;              // 6*196608 = 1179648 f

  prep_kernel<<<571, 256, 0, stream>>>(s, w_b, w_q, w_k, w_v, w_qp, w_kp, w_vp, w_out,
                                       s_bf, wbbf, WT, w_outT);
  gemm_bf16_kernel<<<dim3(9,4), 256, 0, stream>>>(s_bf, WT, P, nullptr, 512, 1152, 384);
  transform_kernel<<<64, 256, 0, stream>>>(P, T, kT, kpgT, qpg, vcatH);
  attn_part_kernel<<<2048, 256, 0, stream>>>(P, qpg, kT, kpgT, wbbf, z, vcatH, gamma, partb);
  combine_kernel<<<512, 256, 0, stream>>>(partb, T, cat);
  gemm_splitk_kernel<<<dim3(3,4,6), 256, 0, stream>>>(cat, w_outT, Cpart, 512, 384, 2112, 352);
  reduce6_kernel<<<768, 256, 0, stream>>>(Cpart, b_out, (float*)d_out);
}

// Round 19
// 103.030 us; speedup vs baseline: 1.4334x; 1.0254x over previous
//
#include <hip/hip_runtime.h>
#include <hip/hip_bf16.h>

typedef __attribute__((ext_vector_type(8))) short short8v;
typedef __attribute__((ext_vector_type(4))) float f32x4;

__device__ __forceinline__ short f2bf(float f){
  unsigned u = __builtin_bit_cast(unsigned, f);
  u += 0x7fffu + ((u >> 16) & 1u);
  return (short)(u >> 16);
}
__device__ __forceinline__ float bf2f(unsigned short s){
  unsigned u = ((unsigned)s) << 16;
  return __builtin_bit_cast(float, u);
}

__device__ __forceinline__ void gload16(const short* g, short* l){
  __builtin_amdgcn_global_load_lds(
    (const __attribute__((address_space(1))) unsigned int*)g,
    (__attribute__((address_space(3))) unsigned int*)l,
    16, 0, 0);
}

// ---------------- fused prep: cast s, wbbf table, both weight transposes ----------------
__global__ __launch_bounds__(256) void prep_kernel(
    const float* __restrict__ s, const float* __restrict__ w_b,
    const float* __restrict__ wq, const float* __restrict__ wk, const float* __restrict__ wv,
    const float* __restrict__ wqp, const float* __restrict__ wkp, const float* __restrict__ wvp,
    const float* __restrict__ w_out,
    short* __restrict__ s_bf, short* __restrict__ wbbf,
    short* __restrict__ WT, short* __restrict__ w_outT)
{
  __shared__ float tsh[64][65];
  int b = blockIdx.x;
  if (b < 192) {
    int gid = b*256 + threadIdx.x;
    float4 f = *(const float4*)(s + (size_t)gid*4);
    short4 o = make_short4(f2bf(f.x), f2bf(f.y), f2bf(f.z), f2bf(f.w));
    *(short4*)(s_bf + (size_t)gid*4) = o;
  } else if (b == 192) {
    const float wL = 0.57735026918962576f;
    for (int u = threadIdx.x; u < 2048; u += 256) {
      int h = u >> 7, zc = u & 127;
      float v = (h < 12) ? w_b[zc*12 + h]*wL : 0.f;
      wbbf[u] = f2bf(v);
    }
  } else if (b < 373) {
    int t = b - 193;
    int n0 = (t % 5)*64, k0 = ((t/5) % 6)*64, src = t/30;
    const float* in; int N; int rowoff;
    switch (src) {
      case 0: in = wq;  N = 192; rowoff = 0;   break;
      case 1: in = wk;  N = 192; rowoff = 192; break;
      case 2: in = wv;  N = 192; rowoff = 384; break;
      case 3: in = wqp; N = 144; rowoff = 576; break;
      case 4: in = wkp; N = 144; rowoff = 720; break;
      default:in = wvp; N = 288; rowoff = 864; break;
    }
    if (n0 >= N) return;
    int lx = threadIdx.x & 15, ly = threadIdx.x >> 4;
    #pragma unroll
    for (int p=0;p<4;++p){
      int r = ly + p*16, c = lx*4;
      float v0=0.f,v1=0.f,v2=0.f,v3=0.f;
      if (n0 + c + 3 < N) {
        float4 v = *(const float4*)(in + (size_t)(k0+r)*N + n0 + c);
        v0=v.x; v1=v.y; v2=v.z; v3=v.w;
      } else {
        if (n0+c+0 < N) v0 = in[(size_t)(k0+r)*N + n0+c+0];
        if (n0+c+1 < N) v1 = in[(size_t)(k0+r)*N + n0+c+1];
        if (n0+c+2 < N) v2 = in[(size_t)(k0+r)*N + n0+c+2];
        if (n0+c+3 < N) v3 = in[(size_t)(k0+r)*N + n0+c+3];
      }
      tsh[c+0][r]=v0; tsh[c+1][r]=v1; tsh[c+2][r]=v2; tsh[c+3][r]=v3;
    }
    __syncthreads();
    #pragma unroll
    for (int p=0;p<4;++p){
      int nr = ly + p*16, kc = lx*4;
      if (n0 + nr < N) {
        short4 o = make_short4(f2bf(tsh[nr][kc]), f2bf(tsh[nr][kc+1]),
                               f2bf(tsh[nr][kc+2]), f2bf(tsh[nr][kc+3]));
        *(short4*)(WT + (size_t)(rowoff+n0+nr)*384 + k0 + kc) = o;
      }
    }
  } else {
    int t = b - 373;
    int n0 = (t % 6)*64, k0 = (t/6)*64;
    int lx = threadIdx.x & 15, ly = threadIdx.x >> 4;
    #pragma unroll
    for (int p=0;p<4;++p){
      int r = ly + p*16, c = lx*4;
      float4 v = *(const float4*)(w_out + (size_t)(k0+r)*384 + n0 + c);
      tsh[c+0][r]=v.x; tsh[c+1][r]=v.y; tsh[c+2][r]=v.z; tsh[c+3][r]=v.w;
    }
    __syncthreads();
    #pragma unroll
    for (int p=0;p<4;++p){
      int nr = ly + p*16, kc = lx*4;
      short4 o = make_short4(f2bf(tsh[nr][kc]), f2bf(tsh[nr][kc+1]),
                             f2bf(tsh[nr][kc+2]), f2bf(tsh[nr][kc+3]));
      *(short4*)(w_outT + (size_t)(n0+nr)*2112 + k0 + kc) = o;
    }
  }
}

// ---------------- bf16 MFMA GEMM: C[M][N] = A[M][K] @ BT[N][K]^T ----------------
__global__ __launch_bounds__(256) void gemm_bf16_kernel(
    const short* __restrict__ A, const short* __restrict__ BT,
    float* __restrict__ C, const float* __restrict__ bias,
    int M, int N, int K)
{
  __shared__ __align__(16) short As[2][4096];
  __shared__ __align__(16) short Bs[2][4096];
  int tid = threadIdx.x;
  int n0 = blockIdx.x*128, m0 = blockIdx.y*128;
  int w = tid >> 6, lane = tid & 63;
  int wr = w >> 1, wc = w & 1;
  int lrow = lane & 15, kg = lane >> 4;
  int nt = K >> 5;
  f32x4 acc[4][4] = {};

  const short* Abase = A  + (size_t)m0*K;
  const short* Bbase = BT + (size_t)n0*K;
  int sr = tid >> 2, scc = (tid & 3)*8;

  auto stage = [&](int b, int k0){
    const short* Ab = Abase + k0;
    const short* Bb = Bbase + k0;
    gload16(Ab + (size_t)sr*K + scc,      &As[b][tid*8]);
    gload16(Bb + (size_t)sr*K + scc,      &Bs[b][tid*8]);
    gload16(Ab + (size_t)(sr+64)*K + scc, &As[b][2048 + tid*8]);
    gload16(Bb + (size_t)(sr+64)*K + scc, &Bs[b][2048 + tid*8]);
  };

  stage(0, 0);
  for (int kt = 0; kt < nt; ++kt){
    int cb = kt & 1;
    if (kt + 1 < nt){
      stage(cb ^ 1, (kt+1) << 5);
      asm volatile("s_waitcnt vmcnt(4)" ::: "memory");
    } else {
      asm volatile("s_waitcnt vmcnt(0)" ::: "memory");
    }
    __builtin_amdgcn_s_barrier();
    short8v af[4], bfr[4];
    #pragma unroll
    for (int mi=0; mi<4; ++mi)
      af[mi]  = *(const short8v*)&As[cb][(wr*64 + mi*16 + lrow)*32 + kg*8];
    #pragma unroll
    for (int ni=0; ni<4; ++ni)
      bfr[ni] = *(const short8v*)&Bs[cb][(wc*64 + ni*16 + lrow)*32 + kg*8];
    #pragma unroll
    for (int mi=0; mi<4; ++mi)
      #pragma unroll
      for (int ni=0; ni<4; ++ni)
        acc[mi][ni] = __builtin_amdgcn_mfma_f32_16x16x32_bf16(af[mi], bfr[ni], acc[mi][ni], 0, 0, 0);
    __builtin_amdgcn_s_barrier();
  }

  #pragma unroll
  for (int mi=0; mi<4; ++mi)
    #pragma unroll
    for (int ni=0; ni<4; ++ni) {
      int col = n0 + wc*64 + ni*16 + lrow;
      float bv = bias ? bias[col] : 0.f;
      #pragma unroll
      for (int jj=0; jj<4; ++jj) {
        int row = m0 + wr*64 + mi*16 + kg*4 + jj;
        C[(size_t)row*N + col] = acc[mi][ni][jj] + bv;
      }
    }
}

// ---------------- split-K GEMM ----------------
__global__ __launch_bounds__(256) void gemm_splitk_kernel(
    const short* __restrict__ A, const short* __restrict__ BT,
    float* __restrict__ Cpart, int M, int N, int lda, int Kc)
{
  __shared__ __align__(16) short As[2][4096];
  __shared__ __align__(16) short Bs[2][4096];
  int tid = threadIdx.x;
  int n0 = blockIdx.x*128, m0 = blockIdx.y*128;
  int kb = blockIdx.z;
  int w = tid >> 6, lane = tid & 63;
  int wr = w >> 1, wc = w & 1;
  int lrow = lane & 15, kg = lane >> 4;
  int nt = Kc >> 5;
  f32x4 acc[4][4] = {};

  const short* Abase = A  + (size_t)m0*lda + (size_t)kb*Kc;
  const short* Bbase = BT + (size_t)n0*lda + (size_t)kb*Kc;
  int sr = tid >> 2, scc = (tid & 3)*8;

  auto stage = [&](int b, int k0){
    const short* Ab = Abase + k0;
    const short* Bb = Bbase + k0;
    gload16(Ab + (size_t)sr*lda + scc,      &As[b][tid*8]);
    gload16(Bb + (size_t)sr*lda + scc,      &Bs[b][tid*8]);
    gload16(Ab + (size_t)(sr+64)*lda + scc, &As[b][2048 + tid*8]);
    gload16(Bb + (size_t)(sr+64)*lda + scc, &Bs[b][2048 + tid*8]);
  };

  stage(0, 0);
  for (int kt = 0; kt < nt; ++kt){
    int cb = kt & 1;
    if (kt + 1 < nt){
      stage(cb ^ 1, (kt+1) << 5);
      asm volatile("s_waitcnt vmcnt(4)" ::: "memory");
    } else {
      asm volatile("s_waitcnt vmcnt(0)" ::: "memory");
    }
    __builtin_amdgcn_s_barrier();
    short8v af[4], bfr[4];
    #pragma unroll
    for (int mi=0; mi<4; ++mi)
      af[mi]  = *(const short8v*)&As[cb][(wr*64 + mi*16 + lrow)*32 + kg*8];
    #pragma unroll
    for (int ni=0; ni<4; ++ni)
      bfr[ni] = *(const short8v*)&Bs[cb][(wc*64 + ni*16 + lrow)*32 + kg*8];
    #pragma unroll
    for (int mi=0; mi<4; ++mi)
      #pragma unroll
      for (int ni=0; ni<4; ++ni)
        acc[mi][ni] = __builtin_amdgcn_mfma_f32_16x16x32_bf16(af[mi], bfr[ni], acc[mi][ni], 0, 0, 0);
    __builtin_amdgcn_s_barrier();
  }

  float* Cp = Cpart + (size_t)kb*M*N;
  #pragma unroll
  for (int mi=0; mi<4; ++mi)
    #pragma unroll
    for (int ni=0; ni<4; ++ni) {
      int col = n0 + wc*64 + ni*16 + lrow;
      #pragma unroll
      for (int jj=0; jj<4; ++jj) {
        int row = m0 + wr*64 + mi*16 + kg*4 + jj;
        Cp[(size_t)row*N + col] = acc[mi][ni][jj];
      }
    }
}

// ---------------- reduce 6 split-K partials + bias ----------------
__global__ __launch_bounds__(256) void reduce6_kernel(
    const float* __restrict__ Cpart, const float* __restrict__ bias,
    float* __restrict__ out)
{
  int idx = blockIdx.x*256 + threadIdx.x;   // 196608 total
  float v = bias[idx % 384];
  #pragma unroll
  for (int zc = 0; zc < 6; ++zc) v += Cpart[(size_t)zc*196608 + idx];
  out[idx] = v;
}

// ---------------- transform: P -> kT, kpgT, qpg, vcatH (j-major, head-chunked d) ----------------
// vcatH[j][512] bf16: chunk h = [40h,40h+40): 16 o values then 24 opg values; cols 480..511 zero
__global__ __launch_bounds__(256) void transform_kernel(
    const float* __restrict__ P, const float* __restrict__ T,
    float* __restrict__ kT, float* __restrict__ kpgT,
    float* __restrict__ qpg, unsigned short* __restrict__ vcatH)
{
  __shared__ float Ps[8][1160];
  __shared__ float Ts[8][12];
  int tid = threadIdx.x;
  int j0 = blockIdx.x*8;
  for (int u = tid; u < 8*288; u += 256) {
    int r = u / 288, c4 = u % 288;
    *(float4*)&Ps[r][c4*4] = *(const float4*)(P + (size_t)(j0+r)*1152 + c4*4);
  }
  if (tid < 96) {
    int r = tid / 12, e = tid % 12;
    Ts[r][e] = (e < 9) ? T[(j0+r)*16 + (e/3)*4 + (e%3)]
                       : T[(j0+r)*16 + (e-9)*4 + 3];
  }
  __syncthreads();
  for (int u = tid; u < 1536; u += 256) {
    int row = u >> 3, jl = u & 7;
    kT[(size_t)row*512 + j0 + jl] = Ps[jl][192 + row];
  }
  for (int u = tid; u < 1152; u += 256) {
    int e = u >> 3, jl = u & 7;
    int x = e % 3, hp = e / 3;
    const float* R = &Ts[jl][0];
    float kx = Ps[jl][720+hp*3], ky = Ps[jl][720+hp*3+1], kz = Ps[jl][720+hp*3+2];
    kpgT[(size_t)e*512 + j0 + jl] = R[x*3]*kx + R[x*3+1]*ky + R[x*3+2]*kz + Ts[jl][9+x];
  }
  for (int u = tid; u < 1152; u += 256) {
    int jl = u / 144, e = u % 144;
    int x = e % 3, hp = e / 3;
    const float* R = &Ts[jl][0];
    float qx = Ps[jl][576+hp*3], qy = Ps[jl][576+hp*3+1], qz = Ps[jl][576+hp*3+2];
    qpg[(size_t)(j0+jl)*144 + e] = R[x*3]*qx + R[x*3+1]*qy + R[x*3+2]*qz + Ts[jl][9+x];
  }
  // vcatH: per (jl, chunk-index)
  for (int u = tid; u < 4096; u += 256) {
    int jl = u >> 9, dn = u & 511;
    float val = 0.f;
    if (dn < 480) {
      int h = dn / 40, c = dn % 40;
      if (c < 16) {
        val = Ps[jl][384 + h*16 + c];              // v
      } else {
        int e = c - 16;                             // 0..23 within head
        int x = e % 3, hp = e / 3;
        const float* R = &Ts[jl][0];
        float vx = Ps[jl][864+h*24+hp*3], vy = Ps[jl][864+h*24+hp*3+1], vz = Ps[jl][864+h*24+hp*3+2];
        val = R[x*3]*vx + R[x*3+1]*vy + R[x*3+2]*vz + Ts[jl][9+x];
      }
    }
    vcatH[(size_t)(j0+jl)*512 + dn] = (unsigned short)f2bf(val);
  }
}

// ---------------- attn partials: block = (i, jq), 128 j each ----------------
// part layout per block (stride 2048 f32):
//   [0:12) m, [12:24) S, [24:504) o+opg in HEAD-CHUNK order (40h+c), [512:2048) o_pair f32
// LDS: un[16384] shorts = zbT (P0a..P4) then ppart[4][512] f32 (P3..reduce)
__global__ __launch_bounds__(256) void attn_part_kernel(
    const float* __restrict__ P, const float* __restrict__ qpg,
    const float* __restrict__ kT, const float* __restrict__ kpgT,
    const short* __restrict__ wbbf, const float* __restrict__ z,
    const unsigned short* __restrict__ vcatH,
    const float* __restrict__ gamma, float* __restrict__ part)
{
  __shared__ __align__(16) short un[16384];    // union: zbT then ppart
  __shared__ float sc[12][132];
  __shared__ float qrow[192], qpgrow[144], gsp[12];
  int bid = blockIdx.x;
  int i = bid >> 2, jq = bid & 3;
  int j0 = jq * 128;
  int tid = threadIdx.x;
  float* pb = part + (size_t)bid * 2048;
  const float* zslab = z + (size_t)i*65536 + (size_t)j0*128;  // [128 j][128 zc]

  if (tid < 192) qrow[tid] = P[(size_t)i*1152 + tid];
  if (tid < 144) qpgrow[tid] = qpg[(size_t)i*144 + tid];
  if (tid < 12)  { float g = gamma[tid]; gsp[tid] = log1pf(__expf(g)); }

  // P0a: stage zbT bf16 with 16B-chunk XOR swizzle (chunk ^= (zc&15)^(zc>>4))
  {
    short* zbT = un;
    int q = tid & 31, jb = tid >> 5;
    for (int r = 0; r < 16; ++r) {
      int jj = jb + r*8;
      float4 f = *(const float4*)(zslab + (size_t)jj*128 + q*4);
      short wv0 = f2bf(f.x), wv1 = f2bf(f.y), wv2 = f2bf(f.z), wv3 = f2bf(f.w);
      int jc = jj >> 3, jr = jj & 7;
      int zc = q*4;
      zbT[(zc+0)*128 + ((jc ^ (((zc+0)&15)^((zc+0)>>4))) << 3) + jr] = wv0;
      zbT[(zc+1)*128 + ((jc ^ (((zc+1)&15)^((zc+1)>>4))) << 3) + jr] = wv1;
      zbT[(zc+2)*128 + ((jc ^ (((zc+2)&15)^((zc+2)>>4))) << 3) + jr] = wv2;
      zbT[(zc+3)*128 + ((jc ^ (((zc+3)&15)^((zc+3)>>4))) << 3) + jr] = wv3;
    }
  }

  // P0b: bias via skinny MFMA — seed sc[h][j] with wL*(z@w_b)
  {
    int w = tid >> 6, lane = tid & 63;
    int lrow = lane & 15, kg = lane >> 4;
    #pragma unroll
    for (int sub = 0; sub < 2; ++sub) {
      int m = w*2 + sub;
      const float* zr = zslab + (size_t)(m*16 + lrow)*128;
      f32x4 acc = {0.f,0.f,0.f,0.f};
      #pragma unroll
      for (int ks = 0; ks < 4; ++ks) {
        int c0 = ks*32 + kg*8;
        float4 z0 = *(const float4*)(zr + c0);
        float4 z1 = *(const float4*)(zr + c0 + 4);
        short8v af;
        af[0]=f2bf(z0.x); af[1]=f2bf(z0.y); af[2]=f2bf(z0.z); af[3]=f2bf(z0.w);
        af[4]=f2bf(z1.x); af[5]=f2bf(z1.y); af[6]=f2bf(z1.z); af[7]=f2bf(z1.w);
        short8v bfv = *(const short8v*)(wbbf + lrow*128 + c0);
        acc = __builtin_amdgcn_mfma_f32_16x16x32_bf16(af, bfv, acc, 0, 0, 0);
      }
      if (lrow < 12) {
        #pragma unroll
        for (int r=0;r<4;++r)
          sc[lrow][m*16 + kg*4 + r] = acc[r];
      }
    }
  }
  __syncthreads();

  // P1: logits for 12 heads over this j-slice (sc pre-seeded with bias)
  {
    int j = tid & 127, hh = tid >> 7;
    const float wL = 0.57735026918962576f;
    const float wC = 0.23570226039551584f;
    #pragma unroll
    for (int hl = 0; hl < 6; ++hl) {
      int h = hh*6 + hl;
      float dot = 0.f;
      #pragma unroll
      for (int c=0;c<16;++c) dot += qrow[h*16+c] * kT[(size_t)(h*16+c)*512 + j0 + j];
      float d2 = 0.f;
      #pragma unroll
      for (int e=0;e<12;++e){ float d = qpgrow[h*12+e] - kpgT[(size_t)(h*12+e)*512 + j0 + j]; d2 += d*d; }
      sc[h][j] += wL*(dot*0.25f - 0.5f*gsp[h]*wC*d2);
    }
  }
  __syncthreads();

  // P2: partial softmax per head: local max m, unnormalized p, local sum S
  if (tid < 192) {
    int h = tid >> 4, l = tid & 15;
    float v[8]; float m = -1e30f;
    #pragma unroll
    for (int u=0;u<8;++u){ v[u] = sc[h][l + u*16]; m = fmaxf(m, v[u]); }
    #pragma unroll
    for (int s2=1;s2<16;s2<<=1) m = fmaxf(m, __shfl_xor(m, s2));
    float sum = 0.f;
    #pragma unroll
    for (int u=0;u<8;++u){ v[u] = __expf(v[u]-m); sum += v[u]; sc[h][l + u*16] = v[u]; }
    #pragma unroll
    for (int s2=1;s2<16;s2<<=1) sum += __shfl_xor(sum, s2);
    if (l == 0) { pb[h] = m; pb[12+h] = sum; }
  }
  __syncthreads();

  // P4: partial o_pair = sc @ z via MFMA (A = sc rows, B = zbT swizzled) — uses un as zbT
  {
    const short* zbT = un;
    int w = tid >> 6, lane = tid & 63;
    int lrow = lane & 15, kg = lane >> 4;
    short8v afr[4];
    #pragma unroll
    for (int ks = 0; ks < 4; ++ks) {
      int row = lrow < 12 ? lrow : 11;
      const float* sp = &sc[row][ks*32 + kg*8];
      float4 a0 = *(const float4*)sp;
      float4 a1 = *(const float4*)(sp+4);
      short8v a;
      a[0]=f2bf(a0.x); a[1]=f2bf(a0.y); a[2]=f2bf(a0.z); a[3]=f2bf(a0.w);
      a[4]=f2bf(a1.x); a[5]=f2bf(a1.y); a[6]=f2bf(a1.z); a[7]=f2bf(a1.w);
      afr[ks] = a;
    }
    #pragma unroll
    for (int t = 0; t < 2; ++t) {
      int zc = w*32 + t*16 + lrow;
      int sw = (zc & 15) ^ (zc >> 4);
      f32x4 pacc = {0.f,0.f,0.f,0.f};
      #pragma unroll
      for (int ks = 0; ks < 4; ++ks) {
        int chunk = (ks*4 + kg) ^ sw;
        short8v bfv = *(const short8v*)&zbT[zc*128 + (chunk<<3)];
        pacc = __builtin_amdgcn_mfma_f32_16x16x32_bf16(afr[ks], bfv, pacc, 0, 0, 0);
      }
      if (kg < 3) {
        #pragma unroll
        for (int r = 0; r < 4; ++r) {
          int h = kg*4 + r;
          pb[512 + h*128 + zc] = pacc[r];
        }
      }
    }
  }
  __syncthreads();   // zbT dead; un becomes ppart

  // P3: o+opg via vcatH — lane L owns d=8L..8L+7 (one head chunk), wave w owns 32 j.
  {
    float* ppart = (float*)un;               // [4][512]
    int w = tid >> 6, lane = tid & 63;
    int hc = (lane < 60) ? (lane / 5) : 11;
    float acc[8] = {};
    const unsigned short* base = vcatH + (size_t)(j0 + w*32)*512 + lane*8;
    #pragma unroll 4
    for (int jj = 0; jj < 32; ++jj) {
      short8v vv = *(const short8v*)(base + (size_t)jj*512);
      float a = sc[hc][w*32 + jj];
      #pragma unroll
      for (int e=0;e<8;++e) acc[e] += a * bf2f((unsigned short)vv[e]);
    }
    #pragma unroll
    for (int e=0;e<8;++e) ppart[w*512 + lane*8 + e] = acc[e];
  }
  __syncthreads();

  // reduce 4 wave-partials of P3 (head-chunk d order)
  {
    const float* ppart = (const float*)un;
    if (tid < 240) {
      #pragma unroll
      for (int rr=0; rr<2; ++rr) {
        int d = tid + rr*240;
        pb[24 + d] = ppart[d] + ppart[512+d] + ppart[1024+d] + ppart[1536+d];
      }
    }
  }
}

// ---------------- combine partials -> cat row (head-chunk o/opg order) ----------------
__global__ __launch_bounds__(256) void combine_kernel(
    const float* __restrict__ part, const float* __restrict__ T,
    short* __restrict__ cat)
{
  __shared__ float w4[4][12], inv[12];
  __shared__ float opgf[288];
  __shared__ float Ri[9], ti[3];
  int i = blockIdx.x, tid = threadIdx.x;
  const float* pb = part + (size_t)i * 4 * 2048;

  if (tid < 12) {
    float m0 = pb[tid], m1 = pb[2048+tid], m2 = pb[4096+tid], m3 = pb[6144+tid];
    float mh = fmaxf(fmaxf(m0,m1), fmaxf(m2,m3));
    float w0 = __expf(m0-mh), w1 = __expf(m1-mh), w2 = __expf(m2-mh), w3 = __expf(m3-mh);
    float S = w0*pb[12+tid] + w1*pb[2060+tid] + w2*pb[4108+tid] + w3*pb[6156+tid];
    w4[0][tid]=w0; w4[1][tid]=w1; w4[2][tid]=w2; w4[3][tid]=w3;
    inv[tid] = 1.f/S;
  }
  if (tid >= 64 && tid < 73) { int e = tid-64; Ri[e] = T[i*16 + (e/3)*4 + (e%3)]; }
  if (tid >= 76 && tid < 79) { int e = tid-76; ti[e] = T[i*16 + e*4 + 3]; }
  __syncthreads();

  short* crow = cat + (size_t)i*2112;

  if (tid < 192) {
    int h = tid >> 4, c = tid & 15;
    int dn = 40*h + c;
    float v = w4[0][h]*pb[24+dn] + w4[1][h]*pb[2072+dn]
            + w4[2][h]*pb[4120+dn] + w4[3][h]*pb[6168+dn];
    crow[tid] = f2bf(v * inv[h]);
  }
  for (int u = tid; u < 288; u += 256) {
    int h = u / 24, e = u % 24;
    int dn = 40*h + 16 + e;
    float v = w4[0][h]*pb[24+dn] + w4[1][h]*pb[2072+dn]
            + w4[2][h]*pb[4120+dn] + w4[3][h]*pb[6168+dn];
    opgf[u] = v * inv[h];
  }
  __syncthreads();
  if (tid < 96) {
    float d0 = opgf[tid*3+0]-ti[0], d1 = opgf[tid*3+1]-ti[1], d2v = opgf[tid*3+2]-ti[2];
    float o0 = Ri[0]*d0 + Ri[3]*d1 + Ri[6]*d2v;
    float o1 = Ri[1]*d0 + Ri[4]*d1 + Ri[7]*d2v;
    float o2 = Ri[2]*d0 + Ri[5]*d1 + Ri[8]*d2v;
    crow[192+tid*3+0] = f2bf(o0); crow[192+tid*3+1] = f2bf(o1); crow[192+tid*3+2] = f2bf(o2);
    crow[480+tid] = f2bf(sqrtf(o0*o0 + o1*o1 + o2*o2 + 1e-8f));
  }
  for (int u = tid; u < 1536; u += 256) {
    int h = u >> 7;
    float v = w4[0][h]*pb[512+u] + w4[1][h]*pb[2560+u]
            + w4[2][h]*pb[4608+u] + w4[3][h]*pb[6656+u];
    crow[576+u] = f2bf(v * inv[h]);
  }
}

// ---------------- launch ----------------
extern "C" void kernel_launch(void* const* d_in, const int* in_sizes, int n_in,
                              void* d_out, int out_size, void* d_ws, size_t ws_size,
                              hipStream_t stream) {
  const float* s     = (const float*)d_in[0];
  const float* z     = (const float*)d_in[1];
  const float* T     = (const float*)d_in[2];
  const float* w_q   = (const float*)d_in[3];
  const float* w_k   = (const float*)d_in[4];
  const float* w_v   = (const float*)d_in[5];
  const float* w_qp  = (const float*)d_in[6];
  const float* w_kp  = (const float*)d_in[7];
  const float* w_vp  = (const float*)d_in[8];
  const float* w_b   = (const float*)d_in[9];
  const float* gamma = (const float*)d_in[10];
  const float* w_out = (const float*)d_in[11];
  const float* b_out = (const float*)d_in[12];

  float* ws = (float*)d_ws;
  float* P      = ws;                        // 589824
  float* kT     = ws + 589824;               // 98304
  float* kpgT   = ws + 688128;               // 73728
  float* qpg    = ws + 761856;               // 73728
  short* wbbf   = (short*)(ws + 835584);     // 2048 sh (1024 f)
  short* s_bf   = (short*)(ws + 836608);     // 196608 sh (98304 f)
  short* WT     = (short*)(ws + 934912);     // 442368 sh (221184 f)
  short* w_outT = (short*)(ws + 1156096);    // 811008 sh (405504 f)
  unsigned short* vcatH = (unsigned short*)(ws + 1561600); // 262144 sh (131072 f)
  short* cat    = (short*)(ws + 1692672);    // 1081344 sh (540672 f)
  float* partb  = ws + 2233344;              // 2048*2048 = 4194304 f
  float* Cpart  = ws + 6427648;              // 6*196608 = 1179648 f

  prep_kernel<<<571, 256, 0, stream>>>(s, w_b, w_q, w_k, w_v, w_qp, w_kp, w_vp, w_out,
                                       s_bf, wbbf, WT, w_outT);
  gemm_bf16_kernel<<<dim3(9,4), 256, 0, stream>>>(s_bf, WT, P, nullptr, 512, 1152, 384);
  transform_kernel<<<64, 256, 0, stream>>>(P, T, kT, kpgT, qpg, vcatH);
  attn_part_kernel<<<2048, 256, 0, stream>>>(P, qpg, kT, kpgT, wbbf, z, vcatH, gamma, partb);
  combine_kernel<<<512, 256, 0, stream>>>(partb, T, cat);
  gemm_splitk_kernel<<<dim3(3,4,6), 256, 0, stream>>>(cat, w_outT, Cpart, 512, 384, 2112, 352);
  reduce6_kernel<<<768, 256, 0, stream>>>(Cpart, b_out, (float*)d_out);
}

// Round 20
// 95.507 us; speedup vs baseline: 1.5463x; 1.0788x over previous
//
#include <hip/hip_runtime.h>
#include <hip/hip_bf16.h>

typedef __attribute__((ext_vector_type(8))) short short8v;
typedef __attribute__((ext_vector_type(4))) float f32x4;

__device__ __forceinline__ short f2bf(float f){
  unsigned u = __builtin_bit_cast(unsigned, f);
  u += 0x7fffu + ((u >> 16) & 1u);
  return (short)(u >> 16);
}
__device__ __forceinline__ float bf2f(unsigned short s){
  unsigned u = ((unsigned)s) << 16;
  return __builtin_bit_cast(float, u);
}

__device__ __forceinline__ void gload16(const short* g, short* l){
  __builtin_amdgcn_global_load_lds(
    (const __attribute__((address_space(1))) unsigned int*)g,
    (__attribute__((address_space(3))) unsigned int*)l,
    16, 0, 0);
}

// ---------------- fused prep: cast s, wbbf table, both weight transposes ----------------
__global__ __launch_bounds__(256) void prep_kernel(
    const float* __restrict__ s, const float* __restrict__ w_b,
    const float* __restrict__ wq, const float* __restrict__ wk, const float* __restrict__ wv,
    const float* __restrict__ wqp, const float* __restrict__ wkp, const float* __restrict__ wvp,
    const float* __restrict__ w_out,
    short* __restrict__ s_bf, short* __restrict__ wbbf,
    short* __restrict__ WT, short* __restrict__ w_outT)
{
  __shared__ float tsh[64][65];
  int b = blockIdx.x;
  if (b < 192) {
    int gid = b*256 + threadIdx.x;
    float4 f = *(const float4*)(s + (size_t)gid*4);
    short4 o = make_short4(f2bf(f.x), f2bf(f.y), f2bf(f.z), f2bf(f.w));
    *(short4*)(s_bf + (size_t)gid*4) = o;
  } else if (b == 192) {
    const float wL = 0.57735026918962576f;
    for (int u = threadIdx.x; u < 2048; u += 256) {
      int h = u >> 7, zc = u & 127;
      float v = (h < 12) ? w_b[zc*12 + h]*wL : 0.f;
      wbbf[u] = f2bf(v);
    }
  } else if (b < 373) {
    int t = b - 193;
    int n0 = (t % 5)*64, k0 = ((t/5) % 6)*64, src = t/30;
    const float* in; int N; int rowoff;
    switch (src) {
      case 0: in = wq;  N = 192; rowoff = 0;   break;
      case 1: in = wk;  N = 192; rowoff = 192; break;
      case 2: in = wv;  N = 192; rowoff = 384; break;
      case 3: in = wqp; N = 144; rowoff = 576; break;
      case 4: in = wkp; N = 144; rowoff = 720; break;
      default:in = wvp; N = 288; rowoff = 864; break;
    }
    if (n0 >= N) return;
    int lx = threadIdx.x & 15, ly = threadIdx.x >> 4;
    #pragma unroll
    for (int p=0;p<4;++p){
      int r = ly + p*16, c = lx*4;
      float v0=0.f,v1=0.f,v2=0.f,v3=0.f;
      if (n0 + c + 3 < N) {
        float4 v = *(const float4*)(in + (size_t)(k0+r)*N + n0 + c);
        v0=v.x; v1=v.y; v2=v.z; v3=v.w;
      } else {
        if (n0+c+0 < N) v0 = in[(size_t)(k0+r)*N + n0+c+0];
        if (n0+c+1 < N) v1 = in[(size_t)(k0+r)*N + n0+c+1];
        if (n0+c+2 < N) v2 = in[(size_t)(k0+r)*N + n0+c+2];
        if (n0+c+3 < N) v3 = in[(size_t)(k0+r)*N + n0+c+3];
      }
      tsh[c+0][r]=v0; tsh[c+1][r]=v1; tsh[c+2][r]=v2; tsh[c+3][r]=v3;
    }
    __syncthreads();
    #pragma unroll
    for (int p=0;p<4;++p){
      int nr = ly + p*16, kc = lx*4;
      if (n0 + nr < N) {
        short4 o = make_short4(f2bf(tsh[nr][kc]), f2bf(tsh[nr][kc+1]),
                               f2bf(tsh[nr][kc+2]), f2bf(tsh[nr][kc+3]));
        *(short4*)(WT + (size_t)(rowoff+n0+nr)*384 + k0 + kc) = o;
      }
    }
  } else {
    int t = b - 373;
    int n0 = (t % 6)*64, k0 = (t/6)*64;
    int lx = threadIdx.x & 15, ly = threadIdx.x >> 4;
    #pragma unroll
    for (int p=0;p<4;++p){
      int r = ly + p*16, c = lx*4;
      float4 v = *(const float4*)(w_out + (size_t)(k0+r)*384 + n0 + c);
      tsh[c+0][r]=v.x; tsh[c+1][r]=v.y; tsh[c+2][r]=v.z; tsh[c+3][r]=v.w;
    }
    __syncthreads();
    #pragma unroll
    for (int p=0;p<4;++p){
      int nr = ly + p*16, kc = lx*4;
      short4 o = make_short4(f2bf(tsh[nr][kc]), f2bf(tsh[nr][kc+1]),
                             f2bf(tsh[nr][kc+2]), f2bf(tsh[nr][kc+3]));
      *(short4*)(w_outT + (size_t)(n0+nr)*2112 + k0 + kc) = o;
    }
  }
}

// ---------------- bf16 MFMA GEMM: C[M][N] = A[M][K] @ BT[N][K]^T ----------------
__global__ __launch_bounds__(256) void gemm_bf16_kernel(
    const short* __restrict__ A, const short* __restrict__ BT,
    float* __restrict__ C, const float* __restrict__ bias,
    int M, int N, int K)
{
  __shared__ __align__(16) short As[2][4096];
  __shared__ __align__(16) short Bs[2][4096];
  int tid = threadIdx.x;
  int n0 = blockIdx.x*128, m0 = blockIdx.y*128;
  int w = tid >> 6, lane = tid & 63;
  int wr = w >> 1, wc = w & 1;
  int lrow = lane & 15, kg = lane >> 4;
  int nt = K >> 5;
  f32x4 acc[4][4] = {};

  const short* Abase = A  + (size_t)m0*K;
  const short* Bbase = BT + (size_t)n0*K;
  int sr = tid >> 2, scc = (tid & 3)*8;

  auto stage = [&](int b, int k0){
    const short* Ab = Abase + k0;
    const short* Bb = Bbase + k0;
    gload16(Ab + (size_t)sr*K + scc,      &As[b][tid*8]);
    gload16(Bb + (size_t)sr*K + scc,      &Bs[b][tid*8]);
    gload16(Ab + (size_t)(sr+64)*K + scc, &As[b][2048 + tid*8]);
    gload16(Bb + (size_t)(sr+64)*K + scc, &Bs[b][2048 + tid*8]);
  };

  stage(0, 0);
  for (int kt = 0; kt < nt; ++kt){
    int cb = kt & 1;
    if (kt + 1 < nt){
      stage(cb ^ 1, (kt+1) << 5);
      asm volatile("s_waitcnt vmcnt(4)" ::: "memory");
    } else {
      asm volatile("s_waitcnt vmcnt(0)" ::: "memory");
    }
    __builtin_amdgcn_s_barrier();
    short8v af[4], bfr[4];
    #pragma unroll
    for (int mi=0; mi<4; ++mi)
      af[mi]  = *(const short8v*)&As[cb][(wr*64 + mi*16 + lrow)*32 + kg*8];
    #pragma unroll
    for (int ni=0; ni<4; ++ni)
      bfr[ni] = *(const short8v*)&Bs[cb][(wc*64 + ni*16 + lrow)*32 + kg*8];
    #pragma unroll
    for (int mi=0; mi<4; ++mi)
      #pragma unroll
      for (int ni=0; ni<4; ++ni)
        acc[mi][ni] = __builtin_amdgcn_mfma_f32_16x16x32_bf16(af[mi], bfr[ni], acc[mi][ni], 0, 0, 0);
    __builtin_amdgcn_s_barrier();
  }

  #pragma unroll
  for (int mi=0; mi<4; ++mi)
    #pragma unroll
    for (int ni=0; ni<4; ++ni) {
      int col = n0 + wc*64 + ni*16 + lrow;
      float bv = bias ? bias[col] : 0.f;
      #pragma unroll
      for (int jj=0; jj<4; ++jj) {
        int row = m0 + wr*64 + mi*16 + kg*4 + jj;
        C[(size_t)row*N + col] = acc[mi][ni][jj] + bv;
      }
    }
}

// ---------------- split-K GEMM ----------------
__global__ __launch_bounds__(256) void gemm_splitk_kernel(
    const short* __restrict__ A, const short* __restrict__ BT,
    float* __restrict__ Cpart, int M, int N, int lda, int Kc)
{
  __shared__ __align__(16) short As[2][4096];
  __shared__ __align__(16) short Bs[2][4096];
  int tid = threadIdx.x;
  int n0 = blockIdx.x*128, m0 = blockIdx.y*128;
  int kb = blockIdx.z;
  int w = tid >> 6, lane = tid & 63;
  int wr = w >> 1, wc = w & 1;
  int lrow = lane & 15, kg = lane >> 4;
  int nt = Kc >> 5;
  f32x4 acc[4][4] = {};

  const short* Abase = A  + (size_t)m0*lda + (size_t)kb*Kc;
  const short* Bbase = BT + (size_t)n0*lda + (size_t)kb*Kc;
  int sr = tid >> 2, scc = (tid & 3)*8;

  auto stage = [&](int b, int k0){
    const short* Ab = Abase + k0;
    const short* Bb = Bbase + k0;
    gload16(Ab + (size_t)sr*lda + scc,      &As[b][tid*8]);
    gload16(Bb + (size_t)sr*lda + scc,      &Bs[b][tid*8]);
    gload16(Ab + (size_t)(sr+64)*lda + scc, &As[b][2048 + tid*8]);
    gload16(Bb + (size_t)(sr+64)*lda + scc, &Bs[b][2048 + tid*8]);
  };

  stage(0, 0);
  for (int kt = 0; kt < nt; ++kt){
    int cb = kt & 1;
    if (kt + 1 < nt){
      stage(cb ^ 1, (kt+1) << 5);
      asm volatile("s_waitcnt vmcnt(4)" ::: "memory");
    } else {
      asm volatile("s_waitcnt vmcnt(0)" ::: "memory");
    }
    __builtin_amdgcn_s_barrier();
    short8v af[4], bfr[4];
    #pragma unroll
    for (int mi=0; mi<4; ++mi)
      af[mi]  = *(const short8v*)&As[cb][(wr*64 + mi*16 + lrow)*32 + kg*8];
    #pragma unroll
    for (int ni=0; ni<4; ++ni)
      bfr[ni] = *(const short8v*)&Bs[cb][(wc*64 + ni*16 + lrow)*32 + kg*8];
    #pragma unroll
    for (int mi=0; mi<4; ++mi)
      #pragma unroll
      for (int ni=0; ni<4; ++ni)
        acc[mi][ni] = __builtin_amdgcn_mfma_f32_16x16x32_bf16(af[mi], bfr[ni], acc[mi][ni], 0, 0, 0);
    __builtin_amdgcn_s_barrier();
  }

  float* Cp = Cpart + (size_t)kb*M*N;
  #pragma unroll
  for (int mi=0; mi<4; ++mi)
    #pragma unroll
    for (int ni=0; ni<4; ++ni) {
      int col = n0 + wc*64 + ni*16 + lrow;
      #pragma unroll
      for (int jj=0; jj<4; ++jj) {
        int row = m0 + wr*64 + mi*16 + kg*4 + jj;
        Cp[(size_t)row*N + col] = acc[mi][ni][jj];
      }
    }
}

// ---------------- reduce 6 split-K partials + bias ----------------
__global__ __launch_bounds__(256) void reduce6_kernel(
    const float* __restrict__ Cpart, const float* __restrict__ bias,
    float* __restrict__ out)
{
  int idx = blockIdx.x*256 + threadIdx.x;   // 196608 total
  float v = bias[idx % 384];
  #pragma unroll
  for (int zc = 0; zc < 6; ++zc) v += Cpart[(size_t)zc*196608 + idx];
  out[idx] = v;
}

// ---------------- transform: P -> kT, kpgT, qpg, vcatH (j-major, head-chunked d) ----------------
// vcatH[j][512] bf16: chunk h = [40h,40h+40): 16 o values then 24 opg values; cols 480..511 zero
__global__ __launch_bounds__(256) void transform_kernel(
    const float* __restrict__ P, const float* __restrict__ T,
    float* __restrict__ kT, float* __restrict__ kpgT,
    float* __restrict__ qpg, unsigned short* __restrict__ vcatH)
{
  __shared__ float Ps[8][1160];
  __shared__ float Ts[8][12];
  int tid = threadIdx.x;
  int j0 = blockIdx.x*8;
  for (int u = tid; u < 8*288; u += 256) {
    int r = u / 288, c4 = u % 288;
    *(float4*)&Ps[r][c4*4] = *(const float4*)(P + (size_t)(j0+r)*1152 + c4*4);
  }
  if (tid < 96) {
    int r = tid / 12, e = tid % 12;
    Ts[r][e] = (e < 9) ? T[(j0+r)*16 + (e/3)*4 + (e%3)]
                       : T[(j0+r)*16 + (e-9)*4 + 3];
  }
  __syncthreads();
  for (int u = tid; u < 1536; u += 256) {
    int row = u >> 3, jl = u & 7;
    kT[(size_t)row*512 + j0 + jl] = Ps[jl][192 + row];
  }
  for (int u = tid; u < 1152; u += 256) {
    int e = u >> 3, jl = u & 7;
    int x = e % 3, hp = e / 3;
    const float* R = &Ts[jl][0];
    float kx = Ps[jl][720+hp*3], ky = Ps[jl][720+hp*3+1], kz = Ps[jl][720+hp*3+2];
    kpgT[(size_t)e*512 + j0 + jl] = R[x*3]*kx + R[x*3+1]*ky + R[x*3+2]*kz + Ts[jl][9+x];
  }
  for (int u = tid; u < 1152; u += 256) {
    int jl = u / 144, e = u % 144;
    int x = e % 3, hp = e / 3;
    const float* R = &Ts[jl][0];
    float qx = Ps[jl][576+hp*3], qy = Ps[jl][576+hp*3+1], qz = Ps[jl][576+hp*3+2];
    qpg[(size_t)(j0+jl)*144 + e] = R[x*3]*qx + R[x*3+1]*qy + R[x*3+2]*qz + Ts[jl][9+x];
  }
  // vcatH: per (jl, chunk-index)
  for (int u = tid; u < 4096; u += 256) {
    int jl = u >> 9, dn = u & 511;
    float val = 0.f;
    if (dn < 480) {
      int h = dn / 40, c = dn % 40;
      if (c < 16) {
        val = Ps[jl][384 + h*16 + c];              // v
      } else {
        int e = c - 16;                             // 0..23 within head
        int x = e % 3, hp = e / 3;
        const float* R = &Ts[jl][0];
        float vx = Ps[jl][864+h*24+hp*3], vy = Ps[jl][864+h*24+hp*3+1], vz = Ps[jl][864+h*24+hp*3+2];
        val = R[x*3]*vx + R[x*3+1]*vy + R[x*3+2]*vz + Ts[jl][9+x];
      }
    }
    vcatH[(size_t)(j0+jl)*512 + dn] = (unsigned short)f2bf(val);
  }
}

// ---------------- attn partials: block = (i, jq), 128 j each ----------------
// part layout per block (stride 2048 f32):
//   [0:12) m, [12:24) S, [24:504) o+opg in HEAD-CHUNK order (40h+c), [512:2048) o_pair f32
// LDS: un[16384] shorts = zbT (P0..P4) then ppart[4][512] f32 (P3..reduce)
__global__ __launch_bounds__(256) void attn_part_kernel(
    const float* __restrict__ P, const float* __restrict__ qpg,
    const float* __restrict__ kT, const float* __restrict__ kpgT,
    const short* __restrict__ wbbf, const float* __restrict__ z,
    const unsigned short* __restrict__ vcatH,
    const float* __restrict__ gamma, float* __restrict__ part)
{
  __shared__ __align__(16) short un[16384];    // union: zbT then ppart
  __shared__ float sc[12][132];
  __shared__ float qrow[192], qpgrow[144], gsp[12];
  int bid = blockIdx.x;
  int i = bid >> 2, jq = bid & 3;
  int j0 = jq * 128;
  int tid = threadIdx.x;
  float* pb = part + (size_t)bid * 2048;
  const float* zslab = z + (size_t)i*65536 + (size_t)j0*128;  // [128 j][128 zc]

  if (tid < 192) qrow[tid] = P[(size_t)i*1152 + tid];
  if (tid < 144) qpgrow[tid] = qpg[(size_t)i*144 + tid];
  if (tid < 12)  { float g = gamma[tid]; gsp[tid] = log1pf(__expf(g)); }

  // P0 (fused): bias via skinny MFMA; each loaded z row-chunk ALSO staged to zbT
  // (single read of the z slab; write swizzle matches P4's read swizzle)
  {
    short* zbT = un;
    int w = tid >> 6, lane = tid & 63;
    int lrow = lane & 15, kg = lane >> 4;
    #pragma unroll
    for (int sub = 0; sub < 2; ++sub) {
      int m = w*2 + sub;
      int j = m*16 + lrow;
      int jc = j >> 3, jr = j & 7;
      const float* zr = zslab + (size_t)j*128;
      f32x4 acc = {0.f,0.f,0.f,0.f};
      #pragma unroll
      for (int ks = 0; ks < 4; ++ks) {
        int c0 = ks*32 + kg*8;
        float4 z0 = *(const float4*)(zr + c0);
        float4 z1 = *(const float4*)(zr + c0 + 4);
        short8v af;
        af[0]=f2bf(z0.x); af[1]=f2bf(z0.y); af[2]=f2bf(z0.z); af[3]=f2bf(z0.w);
        af[4]=f2bf(z1.x); af[5]=f2bf(z1.y); af[6]=f2bf(z1.z); af[7]=f2bf(z1.w);
        #pragma unroll
        for (int e = 0; e < 8; ++e) {
          int zc = c0 + e;
          zbT[zc*128 + ((jc ^ ((zc & 15) ^ (zc >> 4))) << 3) + jr] = af[e];
        }
        short8v bfv = *(const short8v*)(wbbf + lrow*128 + c0);
        acc = __builtin_amdgcn_mfma_f32_16x16x32_bf16(af, bfv, acc, 0, 0, 0);
      }
      if (lrow < 12) {
        #pragma unroll
        for (int r=0;r<4;++r)
          sc[lrow][m*16 + kg*4 + r] = acc[r];
      }
    }
  }
  __syncthreads();

  // P1: logits for 12 heads over this j-slice (sc pre-seeded with bias)
  {
    int j = tid & 127, hh = tid >> 7;
    const float wL = 0.57735026918962576f;
    const float wC = 0.23570226039551584f;
    #pragma unroll
    for (int hl = 0; hl < 6; ++hl) {
      int h = hh*6 + hl;
      float dot = 0.f;
      #pragma unroll
      for (int c=0;c<16;++c) dot += qrow[h*16+c] * kT[(size_t)(h*16+c)*512 + j0 + j];
      float d2 = 0.f;
      #pragma unroll
      for (int e=0;e<12;++e){ float d = qpgrow[h*12+e] - kpgT[(size_t)(h*12+e)*512 + j0 + j]; d2 += d*d; }
      sc[h][j] += wL*(dot*0.25f - 0.5f*gsp[h]*wC*d2);
    }
  }
  __syncthreads();

  // P2: partial softmax per head: local max m, unnormalized p, local sum S
  if (tid < 192) {
    int h = tid >> 4, l = tid & 15;
    float v[8]; float m = -1e30f;
    #pragma unroll
    for (int u=0;u<8;++u){ v[u] = sc[h][l + u*16]; m = fmaxf(m, v[u]); }
    #pragma unroll
    for (int s2=1;s2<16;s2<<=1) m = fmaxf(m, __shfl_xor(m, s2));
    float sum = 0.f;
    #pragma unroll
    for (int u=0;u<8;++u){ v[u] = __expf(v[u]-m); sum += v[u]; sc[h][l + u*16] = v[u]; }
    #pragma unroll
    for (int s2=1;s2<16;s2<<=1) sum += __shfl_xor(sum, s2);
    if (l == 0) { pb[h] = m; pb[12+h] = sum; }
  }
  __syncthreads();

  // P4: partial o_pair = sc @ z via MFMA (A = sc rows, B = zbT swizzled) — uses un as zbT
  {
    const short* zbT = un;
    int w = tid >> 6, lane = tid & 63;
    int lrow = lane & 15, kg = lane >> 4;
    short8v afr[4];
    #pragma unroll
    for (int ks = 0; ks < 4; ++ks) {
      int row = lrow < 12 ? lrow : 11;
      const float* sp = &sc[row][ks*32 + kg*8];
      float4 a0 = *(const float4*)sp;
      float4 a1 = *(const float4*)(sp+4);
      short8v a;
      a[0]=f2bf(a0.x); a[1]=f2bf(a0.y); a[2]=f2bf(a0.z); a[3]=f2bf(a0.w);
      a[4]=f2bf(a1.x); a[5]=f2bf(a1.y); a[6]=f2bf(a1.z); a[7]=f2bf(a1.w);
      afr[ks] = a;
    }
    #pragma unroll
    for (int t = 0; t < 2; ++t) {
      int zc = w*32 + t*16 + lrow;
      int sw = (zc & 15) ^ (zc >> 4);
      f32x4 pacc = {0.f,0.f,0.f,0.f};
      #pragma unroll
      for (int ks = 0; ks < 4; ++ks) {
        int chunk = (ks*4 + kg) ^ sw;
        short8v bfv = *(const short8v*)&zbT[zc*128 + (chunk<<3)];
        pacc = __builtin_amdgcn_mfma_f32_16x16x32_bf16(afr[ks], bfv, pacc, 0, 0, 0);
      }
      if (kg < 3) {
        #pragma unroll
        for (int r = 0; r < 4; ++r) {
          int h = kg*4 + r;
          pb[512 + h*128 + zc] = pacc[r];
        }
      }
    }
  }
  __syncthreads();   // zbT dead; un becomes ppart

  // P3: o+opg via vcatH — lane L owns d=8L..8L+7 (one head chunk), wave w owns 32 j.
  {
    float* ppart = (float*)un;               // [4][512]
    int w = tid >> 6, lane = tid & 63;
    int hc = (lane < 60) ? (lane / 5) : 11;
    float acc[8] = {};
    const unsigned short* base = vcatH + (size_t)(j0 + w*32)*512 + lane*8;
    #pragma unroll 4
    for (int jj = 0; jj < 32; ++jj) {
      short8v vv = *(const short8v*)(base + (size_t)jj*512);
      float a = sc[hc][w*32 + jj];
      #pragma unroll
      for (int e=0;e<8;++e) acc[e] += a * bf2f((unsigned short)vv[e]);
    }
    #pragma unroll
    for (int e=0;e<8;++e) ppart[w*512 + lane*8 + e] = acc[e];
  }
  __syncthreads();

  // reduce 4 wave-partials of P3 (head-chunk d order)
  {
    const float* ppart = (const float*)un;
    if (tid < 240) {
      #pragma unroll
      for (int rr=0; rr<2; ++rr) {
        int d = tid + rr*240;
        pb[24 + d] = ppart[d] + ppart[512+d] + ppart[1024+d] + ppart[1536+d];
      }
    }
  }
}

// ---------------- combine partials -> cat row (head-chunk o/opg order) ----------------
__global__ __launch_bounds__(256) void combine_kernel(
    const float* __restrict__ part, const float* __restrict__ T,
    short* __restrict__ cat)
{
  __shared__ float w4[4][12], inv[12];
  __shared__ float opgf[288];
  __shared__ float Ri[9], ti[3];
  int i = blockIdx.x, tid = threadIdx.x;
  const float* pb = part + (size_t)i * 4 * 2048;

  if (tid < 12) {
    float m0 = pb[tid], m1 = pb[2048+tid], m2 = pb[4096+tid], m3 = pb[6144+tid];
    float mh = fmaxf(fmaxf(m0,m1), fmaxf(m2,m3));
    float w0 = __expf(m0-mh), w1 = __expf(m1-mh), w2 = __expf(m2-mh), w3 = __expf(m3-mh);
    float S = w0*pb[12+tid] + w1*pb[2060+tid] + w2*pb[4108+tid] + w3*pb[6156+tid];
    w4[0][tid]=w0; w4[1][tid]=w1; w4[2][tid]=w2; w4[3][tid]=w3;
    inv[tid] = 1.f/S;
  }
  if (tid >= 64 && tid < 73) { int e = tid-64; Ri[e] = T[i*16 + (e/3)*4 + (e%3)]; }
  if (tid >= 76 && tid < 79) { int e = tid-76; ti[e] = T[i*16 + e*4 + 3]; }
  __syncthreads();

  short* crow = cat + (size_t)i*2112;

  if (tid < 192) {
    int h = tid >> 4, c = tid & 15;
    int dn = 40*h + c;
    float v = w4[0][h]*pb[24+dn] + w4[1][h]*pb[2072+dn]
            + w4[2][h]*pb[4120+dn] + w4[3][h]*pb[6168+dn];
    crow[tid] = f2bf(v * inv[h]);
  }
  for (int u = tid; u < 288; u += 256) {
    int h = u / 24, e = u % 24;
    int dn = 40*h + 16 + e;
    float v = w4[0][h]*pb[24+dn] + w4[1][h]*pb[2072+dn]
            + w4[2][h]*pb[4120+dn] + w4[3][h]*pb[6168+dn];
    opgf[u] = v * inv[h];
  }
  __syncthreads();
  if (tid < 96) {
    float d0 = opgf[tid*3+0]-ti[0], d1 = opgf[tid*3+1]-ti[1], d2v = opgf[tid*3+2]-ti[2];
    float o0 = Ri[0]*d0 + Ri[3]*d1 + Ri[6]*d2v;
    float o1 = Ri[1]*d0 + Ri[4]*d1 + Ri[7]*d2v;
    float o2 = Ri[2]*d0 + Ri[5]*d1 + Ri[8]*d2v;
    crow[192+tid*3+0] = f2bf(o0); crow[192+tid*3+1] = f2bf(o1); crow[192+tid*3+2] = f2bf(o2);
    crow[480+tid] = f2bf(sqrtf(o0*o0 + o1*o1 + o2*o2 + 1e-8f));
  }
  for (int u = tid; u < 1536; u += 256) {
    int h = u >> 7;
    float v = w4[0][h]*pb[512+u] + w4[1][h]*pb[2560+u]
            + w4[2][h]*pb[4608+u] + w4[3][h]*pb[6656+u];
    crow[576+u] = f2bf(v * inv[h]);
  }
}

// ---------------- launch ----------------
extern "C" void kernel_launch(void* const* d_in, const int* in_sizes, int n_in,
                              void* d_out, int out_size, void* d_ws, size_t ws_size,
                              hipStream_t stream) {
  const float* s     = (const float*)d_in[0];
  const float* z     = (const float*)d_in[1];
  const float* T     = (const float*)d_in[2];
  const float* w_q   = (const float*)d_in[3];
  const float* w_k   = (const float*)d_in[4];
  const float* w_v   = (const float*)d_in[5];
  const float* w_qp  = (const float*)d_in[6];
  const float* w_kp  = (const float*)d_in[7];
  const float* w_vp  = (const float*)d_in[8];
  const float* w_b   = (const float*)d_in[9];
  const float* gamma = (const float*)d_in[10];
  const float* w_out = (const float*)d_in[11];
  const float* b_out = (const float*)d_in[12];

  float* ws = (float*)d_ws;
  float* P      = ws;                        // 589824
  float* kT     = ws + 589824;               // 98304
  float* kpgT   = ws + 688128;               // 73728
  float* qpg    = ws + 761856;               // 73728
  short* wbbf   = (short*)(ws + 835584);     // 2048 sh (1024 f)
  short* s_bf   = (short*)(ws + 836608);     // 196608 sh (98304 f)
  short* WT     = (short*)(ws + 934912);     // 442368 sh (221184 f)
  short* w_outT = (short*)(ws + 1156096);    // 811008 sh (405504 f)
  unsigned short* vcatH = (unsigned short*)(ws + 1561600); // 262144 sh (131072 f)
  short* cat    = (short*)(ws + 1692672);    // 1081344 sh (540672 f)
  float* partb  = ws + 2233344;              // 2048*2048 = 4194304 f
  float* Cpart  = ws + 6427648;              // 6*196608 = 1179648 f

  prep_kernel<<<571, 256, 0, stream>>>(s, w_b, w_q, w_k, w_v, w_qp, w_kp, w_vp, w_out,
                                       s_bf, wbbf, WT, w_outT);
  gemm_bf16_kernel<<<dim3(9,4), 256, 0, stream>>>(s_bf, WT, P, nullptr, 512, 1152, 384);
  transform_kernel<<<64, 256, 0, stream>>>(P, T, kT, kpgT, qpg, vcatH);
  attn_part_kernel<<<2048, 256, 0, stream>>>(P, qpg, kT, kpgT, wbbf, z, vcatH, gamma, partb);
  combine_kernel<<<512, 256, 0, stream>>>(partb, T, cat);
  gemm_splitk_kernel<<<dim3(3,4,6), 256, 0, stream>>>(cat, w_outT, Cpart, 512, 384, 2112, 352);
  reduce6_kernel<<<768, 256, 0, stream>>>(Cpart, b_out, (float*)d_out);
}